// Round 8
// baseline (645.175 us; speedup 1.0000x reference)
//
#include <hip/hip_runtime.h>
#include <math.h>

// Problem constants
static constexpr int Bn = 4, Pp = 512, C2 = 256, HEAD = 4, DHd = 64;
static constexpr int Ll = 1024, DIi = 512, Nn = 64, Rr = 16, KCc = 4;

#define DEVI __device__ __forceinline__

DEVI float sigf(float x){ return 1.0f/(1.0f+__expf(-x)); }
DEVI float softplusf(float x){ return x > 20.f ? x : log1pf(__expf(x)); }

// bf16 split helpers (RNE hi, exact residual -> RNE lo)
DEVI unsigned short bfh(float f){
  unsigned int u = __float_as_uint(f);
  return (unsigned short)((u + 0x7FFFu + ((u>>16)&1u)) >> 16);
}
DEVI float bff(unsigned short h){ return __uint_as_float(((unsigned int)h)<<16); }

typedef __attribute__((ext_vector_type(8))) short  bf8v;   // 8 bf16 in 4 VGPRs
typedef __attribute__((ext_vector_type(4))) float  f4v;
typedef __attribute__((ext_vector_type(8))) unsigned short u16x8;

// ---------------- transpose x -> seq (+pos), x2seq ----------------
__global__ void k_transpose(const float* __restrict__ x, const float* __restrict__ rh,
                            const float* __restrict__ rw, float* __restrict__ seq,
                            float* __restrict__ x2seq){
  __shared__ float t[32][33];
  int b = blockIdx.z, c0 = blockIdx.y*32, l0 = blockIdx.x*32;
  for (int i = threadIdx.y; i < 32; i += 8)
    t[i][threadIdx.x] = x[((size_t)(b*Pp + c0 + i)*Ll) + l0 + threadIdx.x];
  __syncthreads();
  for (int i = threadIdx.y; i < 32; i += 8){
    int l = l0 + i, c = c0 + threadIdx.x;
    float v = t[threadIdx.x][i];
    if (c < C2){
      // pos[c,l] = rel_h_c[c, l%32] + rel_w_c[c, l/32]   (ref's (W,H) flatten)
      float pos = rh[c*32 + (l & 31)] + rw[c*32 + (l >> 5)];
      seq[(size_t)(b*Ll + l)*C2 + c] = v + pos;
    } else {
      x2seq[(size_t)(b*Ll + l)*C2 + (c - C2)] = v;
    }
  }
}

// ---------------- split-bf16 MFMA GEMM (single instantiation, BMODE0-only) ------
// C[m,n] = act( sum_k A[m,k]*B[n,k] + bias[n] ),  fp32 in/out, B is (N,K) row-major.
// Requires M%64==0, N%64==0, K%32==0.  Batch via z: base += (z>>2)*s?1 + (z&3)*s?2.
// r6/r7 replay-proven.
__global__ void __launch_bounds__(256) k_mgemmb(
    const float* __restrict__ A, const float* __restrict__ B,
    float* __restrict__ C, const float* __restrict__ bias,
    int M, int N, int K, int lda, int ldb, int ldc,
    long sA1, long sA2, long sB1, long sB2, long sC1, long sC2, int act)
{
  __shared__ __align__(16) unsigned short Ah[64*40], Al[64*40], Bh[64*40], Bl[64*40];
  int z = blockIdx.z;
  const float* Ab = A + (size_t)((z>>2)*sA1 + (z&3)*sA2);
  const float* Bb = B + (size_t)((z>>2)*sB1 + (z&3)*sB2);
  float*       Cb = C + (size_t)((z>>2)*sC1 + (z&3)*sC2);
  int m0 = blockIdx.y*64, n0 = blockIdx.x*64;
  int t = threadIdx.x;
  int w = t >> 6, l = t & 63;
  int g = l >> 4, r = l & 15;
  int row0 = w*16;

  f4v acc[4];
  #pragma unroll
  for (int j=0;j<4;++j) acc[j] = (f4v){0.f,0.f,0.f,0.f};

  int sr = t >> 2;            // 0..63: A row / B col
  int sc = (t & 3) * 8;       // k offset 0,8,16,24

  for (int k0 = 0; k0 < K; k0 += 32){
    // ---- stage A tile ----
    {
      const float* src = Ab + (size_t)(m0+sr)*lda + k0 + sc;
      float4 v0 = *(const float4*)(src);
      float4 v1 = *(const float4*)(src+4);
      float f[8] = {v0.x,v0.y,v0.z,v0.w,v1.x,v1.y,v1.z,v1.w};
      u16x8 hv, lv;
      #pragma unroll
      for (int i=0;i<8;++i){
        unsigned short h = bfh(f[i]); hv[i] = h;
        lv[i] = bfh(f[i] - bff(h));
      }
      *(u16x8*)&Ah[sr*40+sc] = hv;
      *(u16x8*)&Al[sr*40+sc] = lv;
    }
    // ---- stage B tile (as [col][k]) ----
    {
      const float* src = Bb + (size_t)(n0+sr)*ldb + k0 + sc;
      float4 v0 = *(const float4*)(src);
      float4 v1 = *(const float4*)(src+4);
      float f[8] = {v0.x,v0.y,v0.z,v0.w,v1.x,v1.y,v1.z,v1.w};
      u16x8 hv, lv;
      #pragma unroll
      for (int i=0;i<8;++i){
        unsigned short h = bfh(f[i]); hv[i] = h;
        lv[i] = bfh(f[i] - bff(h));
      }
      *(u16x8*)&Bh[sr*40+sc] = hv;
      *(u16x8*)&Bl[sr*40+sc] = lv;
    }
    __syncthreads();
    // ---- compute: wave w owns rows row0..row0+15, frags j over 64 cols ----
    bf8v a_h = *(const bf8v*)&Ah[(row0+r)*40 + g*8];
    bf8v a_l = *(const bf8v*)&Al[(row0+r)*40 + g*8];
    #pragma unroll
    for (int j=0;j<4;++j){
      bf8v b_h = *(const bf8v*)&Bh[(j*16+r)*40 + g*8];
      bf8v b_l = *(const bf8v*)&Bl[(j*16+r)*40 + g*8];
      acc[j] = __builtin_amdgcn_mfma_f32_16x16x32_bf16(a_h, b_h, acc[j], 0, 0, 0);
      acc[j] = __builtin_amdgcn_mfma_f32_16x16x32_bf16(a_h, b_l, acc[j], 0, 0, 0);
      acc[j] = __builtin_amdgcn_mfma_f32_16x16x32_bf16(a_l, b_h, acc[j], 0, 0, 0);
    }
    __syncthreads();
  }
  // ---- epilogue: D frag: col = lane&15, row = (lane>>4)*4 + reg ----
  #pragma unroll
  for (int j=0;j<4;++j){
    int n = n0 + j*16 + r;
    float bv = bias ? bias[n] : 0.f;
    #pragma unroll
    for (int q=0;q<4;++q){
      int m = m0 + row0 + g*4 + q;
      float v = acc[j][q] + bv;
      if (act == 1) v = sigf(v);
      Cb[(size_t)m*ldc + n] = v;
    }
  }
}

// ---------------- fp32 GEMM (BMODE0 only; x_dbl N=144) ----------------
__global__ void __launch_bounds__(256) k_gemm(
       const float* __restrict__ A, const float* __restrict__ B,
       float* __restrict__ C, const float* __restrict__ bias,
       int M, int N, int K, int lda, int ldb, int ldc, int act)
{
  __shared__ float As[16][64];
  __shared__ float Bs[16][64];
  int m0 = blockIdx.y*64, n0 = blockIdx.x*64;
  int t = threadIdx.x, tx = t & 15, ty = t >> 4;
  float acc[4][4] = {};
  int arow = t >> 2, akq = (t & 3) * 4;
  for (int k0 = 0; k0 < K; k0 += 16){
    float4 av = *(const float4*)(A + (size_t)(m0+arow)*lda + k0 + akq);
    As[akq+0][arow] = av.x; As[akq+1][arow] = av.y;
    As[akq+2][arow] = av.z; As[akq+3][arow] = av.w;
    float4 bv = make_float4(0.f,0.f,0.f,0.f);
    if (n0 + arow < N) bv = *(const float4*)(B + (size_t)(n0+arow)*ldb + k0 + akq);
    Bs[akq+0][arow]=bv.x; Bs[akq+1][arow]=bv.y;
    Bs[akq+2][arow]=bv.z; Bs[akq+3][arow]=bv.w;
    __syncthreads();
    #pragma unroll
    for (int k = 0; k < 16; ++k){
      float4 a = *(const float4*)&As[k][ty*4];
      float4 b = *(const float4*)&Bs[k][tx*4];
      acc[0][0] = fmaf(a.x,b.x,acc[0][0]); acc[0][1] = fmaf(a.x,b.y,acc[0][1]);
      acc[0][2] = fmaf(a.x,b.z,acc[0][2]); acc[0][3] = fmaf(a.x,b.w,acc[0][3]);
      acc[1][0] = fmaf(a.y,b.x,acc[1][0]); acc[1][1] = fmaf(a.y,b.y,acc[1][1]);
      acc[1][2] = fmaf(a.y,b.z,acc[1][2]); acc[1][3] = fmaf(a.y,b.w,acc[1][3]);
      acc[2][0] = fmaf(a.z,b.x,acc[2][0]); acc[2][1] = fmaf(a.z,b.y,acc[2][1]);
      acc[2][2] = fmaf(a.z,b.z,acc[2][2]); acc[2][3] = fmaf(a.z,b.w,acc[2][3]);
      acc[3][0] = fmaf(a.w,b.x,acc[3][0]); acc[3][1] = fmaf(a.w,b.y,acc[3][1]);
      acc[3][2] = fmaf(a.w,b.z,acc[3][2]); acc[3][3] = fmaf(a.w,b.w,acc[3][3]);
    }
    __syncthreads();
  }
  #pragma unroll
  for (int i = 0; i < 4; ++i){
    int m = m0 + ty*4 + i;
    #pragma unroll
    for (int j = 0; j < 4; ++j){
      int n = n0 + tx*4 + j;
      if (n < N){
        float v = acc[i][j];
        if (bias) v += bias[n];
        if (act == 1) v = sigf(v);
        else if (act == 2) v = softplusf(v);
        C[(size_t)m*ldc + n] = v;
      }
    }
  }
}

// ---------------- im2col for gate conv (K=3, pad 1) ----------------
__global__ void k_im2col(const float* __restrict__ seq, float* __restrict__ A2){
  int idx = blockIdx.x*256 + threadIdx.x;          // B*L*768
  int j  = idx % 768;
  int bl = idx / 768;
  int kk = j >> 8, c = j & 255;
  int l = bl & 1023, b = bl >> 10;
  int ls = l + kk - 1;
  float v = 0.f;
  if (ls >= 0 && ls < Ll) v = seq[(size_t)(b*Ll + ls)*C2 + c];
  A2[idx] = v;
}

// gate_w (O,I,3) -> W2 (O, kk*256+i)
__global__ void k_packw(const float* __restrict__ gw, float* __restrict__ W2){
  int idx = blockIdx.x*256 + threadIdx.x;          // 256*768
  int j = idx % 768, o = idx / 768;
  int kk = j >> 8, i = j & 255;
  W2[idx] = gw[(size_t)(o*256 + i)*3 + kk];
}

// ---------------- depthwise causal conv (KC=4) + SiLU ----------------
__global__ void k_dwconv(const float* __restrict__ xz, const float* __restrict__ cw,
                         const float* __restrict__ cb, float* __restrict__ xs){
  int idx = blockIdx.x*256 + threadIdx.x;          // B*L*512
  int d = idx & 511; int bl = idx >> 9; int l = bl & 1023; int b = bl >> 10;
  float s = cb[d];
  #pragma unroll
  for (int kk = 0; kk < 4; ++kk){
    int ls = l - 3 + kk;
    if (ls >= 0) s = fmaf(cw[d*4+kk], xz[(size_t)(b*Ll+ls)*1024 + d], s);
  }
  xs[idx] = s * sigf(s);
}

// ---------------- pre-scan: dtT = softplus(xdbl[:, :16]@W_dt^T + b_dt) transposed,
//                  dtuT = dtT * xs^T.  All r/w coalesced. Replaces the dt GEMM.
__global__ void k_pret(const float* __restrict__ xdbl, const float* __restrict__ xs,
                       const float* __restrict__ W_dt, const float* __restrict__ b_dt,
                       float* __restrict__ dtT, float* __restrict__ dtuT){
  __shared__ float X[32][17];    // xdbl[l][r]
  __shared__ float Wd[32][17];   // W_dt[d][r]
  __shared__ float xsb[32][33];  // xs[l][d]
  int b = blockIdx.z, d0 = blockIdx.y*32, l0 = blockIdx.x*32;
  int tx = threadIdx.x, ty = threadIdx.y;           // 32 x 8
  for (int i = ty; i < 32; i += 8){
    if (tx < 16)      X[i][tx]      = xdbl[(size_t)(b*Ll + l0 + i)*144 + tx];
    else              Wd[i][tx-16]  = W_dt[(size_t)(d0 + i)*16 + tx - 16];
    xsb[i][tx] = xs[(size_t)(b*Ll + l0 + i)*512 + d0 + tx];
  }
  __syncthreads();
  for (int dy = ty; dy < 32; dy += 8){
    int d = d0 + dy;
    float v = b_dt[d];
    #pragma unroll
    for (int r = 0; r < 16; ++r) v = fmaf(Wd[dy][r], X[tx][r], v);
    float dt = softplusf(v);
    size_t o = ((size_t)(b*512 + d))*Ll + l0 + tx;
    dtT[o]  = dt;
    dtuT[o] = dt * xsb[tx][dy];
  }
}

// ---------------- selective scan v4: time-major layout, all coalesced ------------
// 1 wave per (b,d). Chunk=32 steps. dtT/dtuT read 128B contiguous; B/C rows from
// L2-resident xdbl; p written to yT coalesced. Epilogue (+Dp*u, *silu(z)) moved
// to k_ytrans. (r7: column-major walk caused 16x read / 8x write amplification.)
__global__ void __launch_bounds__(64) k_scan4(
    const float* __restrict__ dtT, const float* __restrict__ dtuT,
    const float* __restrict__ xdbl, const float* __restrict__ A_log,
    float* __restrict__ yT){
  __shared__ float Bs[32*64];
  __shared__ float Cs[32*64];
  __shared__ float pb[32*65];
  int lane = threadIdx.x;                 // 0..63 (1 wave per block)
  int wid  = blockIdx.x;                  // 0..2047 == b*512+d
  int b = wid >> 9, d = wid & 511;
  float Ac = -__expf(A_log[d*64 + lane]); // per-lane A coefficient
  float h = 0.f;
  size_t base = (size_t)b*Ll;
  size_t bd   = (size_t)wid*Ll;
  int jl = lane & 31;
  bool lo = lane < 32;
  for (int c0 = 0; c0 < Ll; c0 += 32){
    float dtv = 0.f, duv = 0.f;
    if (lo){
      dtv = dtT[bd + c0 + lane];
      duv = dtuT[bd + c0 + lane];
    }
    for (int l = 0; l < 32; ++l){
      size_t r2 = (base + c0 + l)*144;
      Bs[l*64 + lane] = xdbl[r2 + 16 + lane];
      Cs[l*64 + lane] = xdbl[r2 + 80 + lane];
    }
    __syncthreads();
    #pragma unroll
    for (int l = 0; l < 32; ++l){
      float sdt = __shfl(dtv, l);         // lane l (<32) holds step c0+l
      float sdu = __shfl(duv, l);
      float dA = __expf(sdt*Ac);
      h = fmaf(dA, h, sdu*Bs[l*64 + lane]);
      pb[l*65 + lane] = h*Cs[l*64 + lane]; // deferred; off the serial chain
    }
    __syncthreads();
    {
      const float* rp = &pb[jl*65 + (lo ? 0 : 32)];
      float s0=0.f, s1=0.f, s2=0.f, s3=0.f;
      #pragma unroll
      for (int n = 0; n < 32; n += 4){
        s0 += rp[n]; s1 += rp[n+1]; s2 += rp[n+2]; s3 += rp[n+3];
      }
      float p = (s0+s1)+(s2+s3);
      p += __shfl_xor(p, 32);
      if (lo) yT[bd + c0 + jl] = p;
    }
    __syncthreads();
  }
}

// ---------------- yT -> y transpose + scan epilogue fusion ----------------------
// y[bl][d] = (yT[b,d,l] + Dp[d]*xs[bl,d]) * silu(z[bl,d])
__global__ void k_ytrans(const float* __restrict__ yT, const float* __restrict__ xs,
                         const float* __restrict__ xz, const float* __restrict__ D_p,
                         float* __restrict__ y){
  __shared__ float t[32][33];
  int b = blockIdx.z, d0 = blockIdx.y*32, l0 = blockIdx.x*32;
  int tx = threadIdx.x, ty = threadIdx.y;
  for (int i = ty; i < 32; i += 8)
    t[i][tx] = yT[((size_t)(b*512 + d0 + i))*Ll + l0 + tx];
  __syncthreads();
  for (int i = ty; i < 32; i += 8){
    int d = d0 + tx;
    size_t bl = (size_t)b*Ll + l0 + i;
    float p  = t[tx][i];
    float u  = xs[bl*512 + d];
    float zv = xz[bl*1024 + 512 + d];
    y[bl*512 + d] = (p + D_p[d]*u) * (zv * sigf(zv));
  }
}

// ---------------- pack attention A/B operands (K=128 fold) ----------------
__global__ void k_pack_ab(const float* __restrict__ qt, const float* __restrict__ kt,
                          const float* __restrict__ rhm, const float* __restrict__ rwm,
                          float* __restrict__ Ab, float* __restrict__ Bb){
  int idx = blockIdx.x*256 + threadIdx.x;          // B*H*L*128
  int dd = idx & 127;
  int i  = (idx >> 7) & 1023;
  int h  = (idx >> 17) & 3;
  int b  = idx >> 19;
  float av, bv;
  if (dd < 64){
    size_t q = (size_t)(b*Ll + i)*C2 + h*64 + dd;
    av = qt[q]; bv = kt[q];
  } else {
    int d = dd - 64;
    av = rhm[(h*64+d)*32 + (i & 31)] + rwm[(h*64+d)*32 + (i >> 5)];
    bv = qt[(size_t)(b*Ll + i)*C2 + h*64 + d];
  }
  Ab[idx] = av; Bb[idx] = bv;
}

// ---------------- V transpose: vt (B*L,256) -> vT (B,256,L) ----------------
__global__ void k_vtrans(const float* __restrict__ vt, float* __restrict__ vT){
  __shared__ float t[32][33];
  int b = blockIdx.z, c0 = blockIdx.y*32, j0 = blockIdx.x*32;
  for (int i = threadIdx.y; i < 32; i += 8)
    t[i][threadIdx.x] = vt[(size_t)(b*Ll + j0 + i)*C2 + c0 + threadIdx.x];
  __syncthreads();
  for (int i = threadIdx.y; i < 32; i += 8)
    vT[((size_t)(b*C2 + c0 + i))*Ll + j0 + threadIdx.x] = t[threadIdx.x][i];
}

// ---------------- row softmax over 1024 (in place) ----------------
__global__ void __launch_bounds__(256) k_softmax(float* __restrict__ e){
  __shared__ float red[4];
  __shared__ float red2[4];
  size_t row = blockIdx.x;
  float* p = e + row*1024;
  int t = threadIdx.x;
  float v0 = p[t], v1 = p[t+256], v2 = p[t+512], v3 = p[t+768];
  float mx = fmaxf(fmaxf(v0,v1), fmaxf(v2,v3));
  #pragma unroll
  for (int off=32; off; off>>=1) mx = fmaxf(mx, __shfl_xor(mx, off));
  if ((t&63)==0) red[t>>6] = mx;
  __syncthreads();
  mx = fmaxf(fmaxf(red[0],red[1]), fmaxf(red[2],red[3]));
  v0 = __expf(v0-mx); v1 = __expf(v1-mx); v2 = __expf(v2-mx); v3 = __expf(v3-mx);
  float s = v0+v1+v2+v3;
  #pragma unroll
  for (int off=32; off; off>>=1) s += __shfl_xor(s, off);
  if ((t&63)==0) red2[t>>6] = s;
  __syncthreads();
  s = red2[0]+red2[1]+red2[2]+red2[3];
  float inv = 1.0f/s;
  p[t] = v0*inv; p[t+256] = v1*inv; p[t+512] = v2*inv; p[t+768] = v3*inv;
}

// ---------------- fused ym*ctx + reference's reshape-reinterpret ----------------
// out1[b][c][s] = ymctx[b][l = c*4 + (s>>8)][c' = s&255]   (s = h*32+w)
__global__ void k_mulshuf(const float* __restrict__ ym, const float* __restrict__ ctx,
                          float* __restrict__ out1t){
  __shared__ float t[32][33];
  int b = blockIdx.z >> 2, s1 = blockIdx.z & 3;
  int c0 = blockIdx.y*32, s00 = blockIdx.x*32;
  for (int i = threadIdx.y; i < 32; i += 8){
    int c = c0 + i;
    int l = c*4 + s1;
    size_t off = ((size_t)(b*Ll + l))*C2 + s00 + threadIdx.x;
    t[i][threadIdx.x] = ym[off] * ctx[off];
  }
  __syncthreads();
  for (int i = threadIdx.y; i < 32; i += 8){
    int s0 = s00 + i, c = c0 + threadIdx.x;
    int s = s1*256 + s0;
    out1t[((size_t)(b*Ll + s))*C2 + c] = t[threadIdx.x][i];
  }
}

// ---------------- scalar gates ga/gb ----------------
__global__ void __launch_bounds__(256) k_gates(
    const float* __restrict__ ap, const float* __restrict__ bp,
    const float* __restrict__ Wg, const float* __restrict__ bg, float* __restrict__ g){
  __shared__ float ra[4], rb[4];
  int bl = blockIdx.x; int t = threadIdx.x;
  float sa = 0.f, sb = 0.f;
  const float* a = ap + (size_t)bl*512;
  const float* bq = bp + (size_t)bl*512;
  for (int pp = t; pp < 512; pp += 256){ float w = Wg[pp]; sa = fmaf(w, a[pp], sa); sb = fmaf(w, bq[pp], sb); }
  #pragma unroll
  for (int off=32; off; off>>=1){ sa += __shfl_xor(sa,off); sb += __shfl_xor(sb,off); }
  if ((t&63)==0){ ra[t>>6]=sa; rb[t>>6]=sb; }
  __syncthreads();
  if (t==0){
    float b0 = bg[0];
    g[bl]        = sigf(ra[0]+ra[1]+ra[2]+ra[3] + b0);
    g[4096 + bl] = sigf(rb[0]+rb[1]+rb[2]+rb[3] + b0);
  }
}

// ---------------- final gated combine, transposed write ----------------
__global__ void k_final(const float* __restrict__ ap, const float* __restrict__ bp,
                        const float* __restrict__ g, float* __restrict__ out){
  int bpid = blockIdx.x; int b = bpid >> 9, p = bpid & 511;
  for (int l = threadIdx.x; l < Ll; l += 256){
    int bl = b*Ll + l;
    float ga = g[bl], gb = g[4096 + bl];
    out[((size_t)(b*Pp + p) << 10) + l] =
        ga*ap[(size_t)bl*512 + p] + gb*bp[(size_t)bl*512 + p];
  }
}

// ---------------- host side ----------------
static inline void mgemm(hipStream_t s, const float* A, const float* B, float* C,
                         const float* bias, int M, int N, int K, int lda, int ldb, int ldc,
                         int act){
  dim3 g(N/64, M/64, 1), blk(256);
  k_mgemmb<<<g, blk, 0, s>>>(A,B,C,bias,M,N,K,lda,ldb,ldc, 0,0,0,0,0,0, act);
}

extern "C" void kernel_launch(void* const* d_in, const int* in_sizes, int n_in,
                              void* d_out, int out_size, void* d_ws, size_t ws_size,
                              hipStream_t stream) {
  const float* x      = (const float*)d_in[0];
  const float* rh_c   = (const float*)d_in[1];
  const float* rw_c   = (const float*)d_in[2];
  const float* gate_w = (const float*)d_in[3];
  const float* gate_b = (const float*)d_in[4];
  const float* W_in   = (const float*)d_in[5];
  const float* conv_w = (const float*)d_in[6];
  const float* conv_b = (const float*)d_in[7];
  const float* W_x    = (const float*)d_in[8];
  const float* W_dt   = (const float*)d_in[9];
  const float* b_dt   = (const float*)d_in[10];
  const float* A_log  = (const float*)d_in[11];
  const float* D_p    = (const float*)d_in[12];
  const float* W_out  = (const float*)d_in[13];
  const float* Wq     = (const float*)d_in[14];
  const float* bq     = (const float*)d_in[15];
  const float* Wk     = (const float*)d_in[16];
  const float* bk     = (const float*)d_in[17];
  const float* Wv     = (const float*)d_in[18];
  const float* bv     = (const float*)d_in[19];
  const float* rhm    = (const float*)d_in[20];
  const float* rwm    = (const float*)d_in[21];
  // d_in[22] reg_qk, d_in[23] reg_v: provably dead (softmax per-head, head 4 discarded)
  const float* Wa     = (const float*)d_in[24];
  const float* ba     = (const float*)d_in[25];
  const float* Wb     = (const float*)d_in[26];
  const float* bb     = (const float*)d_in[27];
  const float* Wg     = (const float*)d_in[28];
  const float* bg     = (const float*)d_in[29];
  float* out = (float*)d_out;
  float* ws  = (float*)d_ws;

  // ws layout (floats). Total ≈ 131 MB.
  float* seq    = ws;                       // 1,048,576
  float* x2seq  = ws +  1048576;            // 1,048,576
  float* qt     = ws +  2097152;            // 1,048,576
  float* kt     = ws +  3145728;            // 1,048,576
  float* vt     = ws +  4194304;            // 1,048,576
  float* Abuf   = ws +  5242880;            // 2,097,152 (mamba: dtT)
  float* Bbuf   = ws +  7340032;            // 2,097,152 (mamba: dtuT)
  float* arena  = ws +  9437184;            // 16,777,216 (energy OR mamba chain)
  float* out2   = ws + 26214400;            // 1,048,576
  float* out1   = ws + 27262976;            // 1,048,576
  float* aproj  = ws + 28311552;            // 2,097,152 (vT parks here during attention)
  float* bproj  = ws + 30408704;            // 2,097,152
  float* gates  = ws + 32505856;            // 8,192
  float* W2     = ws + 32514048;            // 196,608
  // arena sub-layout (mamba phase, after energy is dead):
  float* A2   = arena;                      // 3,145,728
  float* ctx  = arena +  3145728;           // 1,048,576
  float* xz   = arena +  4194304;           // 4,194,304
  float* xs   = arena +  8388608;           // 2,097,152
  float* xdbl = arena + 10485760;           // 589,824
  float* yT   = arena + 11075584;           // 2,097,152
  float* yb   = arena + 13172736;           // 2,097,152
  float* ym   = arena + 15269888;           // 1,048,576
  float* energy = arena;                    // 16,777,216 (attention phase)
  float* vT   = aproj;                      // 1,048,576 (attention phase only)
  float* dtT  = Abuf;                       // 2,097,152 (mamba phase only)
  float* dtuT = Bbuf;                       // 2,097,152 (mamba phase only)

  // 1. transpose x -> seq(+pos), x2seq
  k_transpose<<<dim3(32,16,4), dim3(32,8), 0, stream>>>(x, rh_c, rw_c, seq, x2seq);

  // ---- attention branch first (uses arena as energy) ----
  // q/k/v = x2seq @ W^T + b   (B*L,256)
  mgemm(stream, x2seq, Wq, qt, bq, 4096,256,256, 256,256,256, 0);
  mgemm(stream, x2seq, Wk, kt, bk, 4096,256,256, 256,256,256, 0);
  mgemm(stream, x2seq, Wv, vt, bv, 4096,256,256, 256,256,256, 0);
  // pack energy operands; transpose V
  k_pack_ab<<<8192, 256, 0, stream>>>(qt, kt, rhm, rwm, Abuf, Bbuf);
  k_vtrans<<<dim3(32,8,4), dim3(32,8), 0, stream>>>(vt, vT);
  // energy[z] = Abuf[z] @ Bbuf[z]^T  (M=N=1024, K=128), z = b*4+h
  {
    dim3 g(16, 16, 16), blk(256);
    k_mgemmb<<<g, blk, 0, stream>>>(Abuf, Bbuf, energy, nullptr,
        1024,1024,128, 128,128,1024,
        4L*131072, 131072, 4L*131072, 131072, 4L*1048576, 1048576, 0);
  }
  // softmax rows
  k_softmax<<<16384, 256, 0, stream>>>(energy);
  // PV via BMODE0: out2[b,i,h*64+d] = sum_j attn[z][i,j] * vT[b, h*64+d, j]
  {
    dim3 g(1, 16, 16), blk(256);
    k_mgemmb<<<g, blk, 0, stream>>>(energy, vT, out2, nullptr,
        1024,64,1024, 1024,1024,256,
        4L*1048576, 1048576, 262144, 65536, 262144, 64, 0);
  }

  // ---- mamba branch (arena reused; Abuf/Bbuf/vT free after PV) ----
  k_packw<<<768, 256, 0, stream>>>(gate_w, W2);
  k_im2col<<<12288, 256, 0, stream>>>(seq, A2);
  // ctx = sigmoid(A2 @ W2^T + gate_b)
  mgemm(stream, A2, W2, ctx, gate_b, 4096,256,768, 768,768,256, 1);
  // xz = seq @ W_in^T
  mgemm(stream, seq, W_in, xz, nullptr, 4096,1024,256, 256,256,1024, 0);
  // xs = silu(depthwise conv(xi))
  k_dwconv<<<8192, 256, 0, stream>>>(xz, conv_w, conv_b, xs);
  // x_dbl = xs @ W_x^T   (N=144 -> fp32 guarded path)
  {
    dim3 g(3, 64, 1), blk(256);
    k_gemm<<<g, blk, 0, stream>>>(xs, W_x, xdbl, nullptr, 4096,144,512, 512,512,144, 0);
  }
  // dtT/dtuT (replaces dt GEMM; time-major for scan)
  k_pret<<<dim3(32,16,4), dim3(32,8), 0, stream>>>(xdbl, xs, W_dt, b_dt, dtT, dtuT);
  // selective scan v4 (coalesced; epilogue deferred to ytrans)
  k_scan4<<<2048, 64, 0, stream>>>(dtT, dtuT, xdbl, A_log, yT);
  // y = (yT^T + Dp*xs) * silu(z)
  k_ytrans<<<dim3(32,16,4), dim3(32,8), 0, stream>>>(yT, xs, xz, D_p, yb);
  // ym = y @ W_out^T
  mgemm(stream, yb, W_out, ym, nullptr, 4096,256,512, 512,512,256, 0);
  // out1t = (ym*ctx) with reference's reshape-reinterpret baked in
  k_mulshuf<<<dim3(8,8,16), dim3(32,8), 0, stream>>>(ym, ctx, out1);

  // ---- fusion head ----
  mgemm(stream, out1, Wa, aproj, ba, 4096,512,256, 256,256,512, 0);
  mgemm(stream, out2, Wb, bproj, bb, 4096,512,256, 256,256,512, 0);
  k_gates<<<4096, 256, 0, stream>>>(aproj, bproj, Wg, bg, gates);
  k_final<<<2048, 256, 0, stream>>>(aproj, bproj, gates, out);
}

// Round 9
// 575.397 us; speedup vs baseline: 1.1213x; 1.1213x over previous
//
#include <hip/hip_runtime.h>
#include <math.h>

// Problem constants
static constexpr int Bn = 4, Pp = 512, C2 = 256, HEAD = 4, DHd = 64;
static constexpr int Ll = 1024, DIi = 512, Nn = 64, Rr = 16, KCc = 4;

#define DEVI __device__ __forceinline__

DEVI float sigf(float x){ return 1.0f/(1.0f+__expf(-x)); }
DEVI float softplusf(float x){ return x > 20.f ? x : log1pf(__expf(x)); }

// bf16 split helpers (RNE hi, exact residual -> RNE lo)
DEVI unsigned short bfh(float f){
  unsigned int u = __float_as_uint(f);
  return (unsigned short)((u + 0x7FFFu + ((u>>16)&1u)) >> 16);
}
DEVI float bff(unsigned short h){ return __uint_as_float(((unsigned int)h)<<16); }

typedef __attribute__((ext_vector_type(8))) short  bf8v;   // 8 bf16 in 4 VGPRs
typedef __attribute__((ext_vector_type(4))) float  f4v;
typedef __attribute__((ext_vector_type(8))) unsigned short u16x8;

// ---------------- transpose x -> seq (+pos), x2seq ----------------
__global__ void k_transpose(const float* __restrict__ x, const float* __restrict__ rh,
                            const float* __restrict__ rw, float* __restrict__ seq,
                            float* __restrict__ x2seq){
  __shared__ float t[32][33];
  int b = blockIdx.z, c0 = blockIdx.y*32, l0 = blockIdx.x*32;
  for (int i = threadIdx.y; i < 32; i += 8)
    t[i][threadIdx.x] = x[((size_t)(b*Pp + c0 + i)*Ll) + l0 + threadIdx.x];
  __syncthreads();
  for (int i = threadIdx.y; i < 32; i += 8){
    int l = l0 + i, c = c0 + threadIdx.x;
    float v = t[threadIdx.x][i];
    if (c < C2){
      float pos = rh[c*32 + (l & 31)] + rw[c*32 + (l >> 5)];
      seq[(size_t)(b*Ll + l)*C2 + c] = v + pos;
    } else {
      x2seq[(size_t)(b*Ll + l)*C2 + (c - C2)] = v;
    }
  }
}

// ---------------- split-bf16 MFMA GEMM, 64x64 tile (r6-r8 replay-proven) --------
// C[m,n] = act( sum_k A[m,k]*B[n,k] + bias[n] ),  B is (N,K) row-major.
// M%64==0, N%64==0, K%32==0. Batch z: base += (z>>2)*s?1 + (z&3)*s?2.
__global__ void __launch_bounds__(256) k_mgemmb(
    const float* __restrict__ A, const float* __restrict__ B,
    float* __restrict__ C, const float* __restrict__ bias,
    int M, int N, int K, int lda, int ldb, int ldc,
    long sA1, long sA2, long sB1, long sB2, long sC1, long sC2, int act)
{
  __shared__ __align__(16) unsigned short Ah[64*40], Al[64*40], Bh[64*40], Bl[64*40];
  int z = blockIdx.z;
  const float* Ab = A + (size_t)((z>>2)*sA1 + (z&3)*sA2);
  const float* Bb = B + (size_t)((z>>2)*sB1 + (z&3)*sB2);
  float*       Cb = C + (size_t)((z>>2)*sC1 + (z&3)*sC2);
  int m0 = blockIdx.y*64, n0 = blockIdx.x*64;
  int t = threadIdx.x;
  int w = t >> 6, l = t & 63;
  int g = l >> 4, r = l & 15;
  int row0 = w*16;

  f4v acc[4];
  #pragma unroll
  for (int j=0;j<4;++j) acc[j] = (f4v){0.f,0.f,0.f,0.f};

  int sr = t >> 2;            // 0..63
  int sc = (t & 3) * 8;       // 0,8,16,24

  for (int k0 = 0; k0 < K; k0 += 32){
    {
      const float* src = Ab + (size_t)(m0+sr)*lda + k0 + sc;
      float4 v0 = *(const float4*)(src);
      float4 v1 = *(const float4*)(src+4);
      float f[8] = {v0.x,v0.y,v0.z,v0.w,v1.x,v1.y,v1.z,v1.w};
      u16x8 hv, lv;
      #pragma unroll
      for (int i=0;i<8;++i){
        unsigned short h = bfh(f[i]); hv[i] = h;
        lv[i] = bfh(f[i] - bff(h));
      }
      *(u16x8*)&Ah[sr*40+sc] = hv;
      *(u16x8*)&Al[sr*40+sc] = lv;
    }
    {
      const float* src = Bb + (size_t)(n0+sr)*ldb + k0 + sc;
      float4 v0 = *(const float4*)(src);
      float4 v1 = *(const float4*)(src+4);
      float f[8] = {v0.x,v0.y,v0.z,v0.w,v1.x,v1.y,v1.z,v1.w};
      u16x8 hv, lv;
      #pragma unroll
      for (int i=0;i<8;++i){
        unsigned short h = bfh(f[i]); hv[i] = h;
        lv[i] = bfh(f[i] - bff(h));
      }
      *(u16x8*)&Bh[sr*40+sc] = hv;
      *(u16x8*)&Bl[sr*40+sc] = lv;
    }
    __syncthreads();
    bf8v a_h = *(const bf8v*)&Ah[(row0+r)*40 + g*8];
    bf8v a_l = *(const bf8v*)&Al[(row0+r)*40 + g*8];
    #pragma unroll
    for (int j=0;j<4;++j){
      bf8v b_h = *(const bf8v*)&Bh[(j*16+r)*40 + g*8];
      bf8v b_l = *(const bf8v*)&Bl[(j*16+r)*40 + g*8];
      acc[j] = __builtin_amdgcn_mfma_f32_16x16x32_bf16(a_h, b_h, acc[j], 0, 0, 0);
      acc[j] = __builtin_amdgcn_mfma_f32_16x16x32_bf16(a_h, b_l, acc[j], 0, 0, 0);
      acc[j] = __builtin_amdgcn_mfma_f32_16x16x32_bf16(a_l, b_h, acc[j], 0, 0, 0);
    }
    __syncthreads();
  }
  #pragma unroll
  for (int j=0;j<4;++j){
    int n = n0 + j*16 + r;
    float bv = bias ? bias[n] : 0.f;
    #pragma unroll
    for (int q=0;q<4;++q){
      int m = m0 + row0 + g*4 + q;
      float v = acc[j][q] + bv;
      if (act == 1) v = sigf(v);
      Cb[(size_t)m*ldc + n] = v;
    }
  }
}

// ---------------- split-bf16 MFMA GEMM, 128x128 tile (energy & xz) --------------
// Same semantics/staging idiom as k_mgemmb; wave w owns rows w*32..w*32+31, all
// 128 cols: acc[2][8], 48 MFMA per wave per K-step. M%128==0, N%128==0, K%32==0.
__global__ void __launch_bounds__(256) k_m128(
    const float* __restrict__ A, const float* __restrict__ B,
    float* __restrict__ C, const float* __restrict__ bias,
    int M, int N, int K, int lda, int ldb, int ldc,
    long sA1, long sA2, long sB1, long sB2, long sC1, long sC2, int act)
{
  __shared__ __align__(16) unsigned short Ah[128*40], Al[128*40], Bh[128*40], Bl[128*40];
  int z = blockIdx.z;
  const float* Ab = A + (size_t)((z>>2)*sA1 + (z&3)*sA2);
  const float* Bb = B + (size_t)((z>>2)*sB1 + (z&3)*sB2);
  float*       Cb = C + (size_t)((z>>2)*sC1 + (z&3)*sC2);
  int m0 = blockIdx.y*128, n0 = blockIdx.x*128;
  int t = threadIdx.x;
  int w = t >> 6, l = t & 63;
  int g = l >> 4, r = l & 15;
  int row0 = w*32;

  f4v acc[2][8];
  #pragma unroll
  for (int i=0;i<2;++i)
    #pragma unroll
    for (int j=0;j<8;++j) acc[i][j] = (f4v){0.f,0.f,0.f,0.f};

  int sr = t >> 1;            // 0..127
  int sc = (t & 1) * 16;      // 0,16

  for (int k0 = 0; k0 < K; k0 += 32){
    {
      const float* src = Ab + (size_t)(m0+sr)*lda + k0 + sc;
      float4 v0 = *(const float4*)(src);
      float4 v1 = *(const float4*)(src+4);
      float4 v2 = *(const float4*)(src+8);
      float4 v3 = *(const float4*)(src+12);
      float f[16] = {v0.x,v0.y,v0.z,v0.w,v1.x,v1.y,v1.z,v1.w,
                     v2.x,v2.y,v2.z,v2.w,v3.x,v3.y,v3.z,v3.w};
      u16x8 hv0, lv0, hv1, lv1;
      #pragma unroll
      for (int i=0;i<8;++i){
        unsigned short h = bfh(f[i]); hv0[i] = h;
        lv0[i] = bfh(f[i] - bff(h));
      }
      #pragma unroll
      for (int i=0;i<8;++i){
        unsigned short h = bfh(f[8+i]); hv1[i] = h;
        lv1[i] = bfh(f[8+i] - bff(h));
      }
      *(u16x8*)&Ah[sr*40+sc]   = hv0;  *(u16x8*)&Ah[sr*40+sc+8] = hv1;
      *(u16x8*)&Al[sr*40+sc]   = lv0;  *(u16x8*)&Al[sr*40+sc+8] = lv1;
    }
    {
      const float* src = Bb + (size_t)(n0+sr)*ldb + k0 + sc;
      float4 v0 = *(const float4*)(src);
      float4 v1 = *(const float4*)(src+4);
      float4 v2 = *(const float4*)(src+8);
      float4 v3 = *(const float4*)(src+12);
      float f[16] = {v0.x,v0.y,v0.z,v0.w,v1.x,v1.y,v1.z,v1.w,
                     v2.x,v2.y,v2.z,v2.w,v3.x,v3.y,v3.z,v3.w};
      u16x8 hv0, lv0, hv1, lv1;
      #pragma unroll
      for (int i=0;i<8;++i){
        unsigned short h = bfh(f[i]); hv0[i] = h;
        lv0[i] = bfh(f[i] - bff(h));
      }
      #pragma unroll
      for (int i=0;i<8;++i){
        unsigned short h = bfh(f[8+i]); hv1[i] = h;
        lv1[i] = bfh(f[8+i] - bff(h));
      }
      *(u16x8*)&Bh[sr*40+sc]   = hv0;  *(u16x8*)&Bh[sr*40+sc+8] = hv1;
      *(u16x8*)&Bl[sr*40+sc]   = lv0;  *(u16x8*)&Bl[sr*40+sc+8] = lv1;
    }
    __syncthreads();
    bf8v a_h0 = *(const bf8v*)&Ah[(row0+r)*40 + g*8];
    bf8v a_l0 = *(const bf8v*)&Al[(row0+r)*40 + g*8];
    bf8v a_h1 = *(const bf8v*)&Ah[(row0+16+r)*40 + g*8];
    bf8v a_l1 = *(const bf8v*)&Al[(row0+16+r)*40 + g*8];
    #pragma unroll
    for (int j=0;j<8;++j){
      bf8v b_h = *(const bf8v*)&Bh[(j*16+r)*40 + g*8];
      bf8v b_l = *(const bf8v*)&Bl[(j*16+r)*40 + g*8];
      acc[0][j] = __builtin_amdgcn_mfma_f32_16x16x32_bf16(a_h0, b_h, acc[0][j], 0, 0, 0);
      acc[0][j] = __builtin_amdgcn_mfma_f32_16x16x32_bf16(a_h0, b_l, acc[0][j], 0, 0, 0);
      acc[0][j] = __builtin_amdgcn_mfma_f32_16x16x32_bf16(a_l0, b_h, acc[0][j], 0, 0, 0);
      acc[1][j] = __builtin_amdgcn_mfma_f32_16x16x32_bf16(a_h1, b_h, acc[1][j], 0, 0, 0);
      acc[1][j] = __builtin_amdgcn_mfma_f32_16x16x32_bf16(a_h1, b_l, acc[1][j], 0, 0, 0);
      acc[1][j] = __builtin_amdgcn_mfma_f32_16x16x32_bf16(a_l1, b_h, acc[1][j], 0, 0, 0);
    }
    __syncthreads();
  }
  #pragma unroll
  for (int i=0;i<2;++i){
    #pragma unroll
    for (int j=0;j<8;++j){
      int n = n0 + j*16 + r;
      float bv = bias ? bias[n] : 0.f;
      #pragma unroll
      for (int q=0;q<4;++q){
        int m = m0 + row0 + i*16 + g*4 + q;
        float v = acc[i][j][q] + bv;
        if (act == 1) v = sigf(v);
        Cb[(size_t)m*ldc + n] = v;
      }
    }
  }
}

// ---------------- fp32 GEMM (x_dbl N=144) ----------------
__global__ void __launch_bounds__(256) k_gemm(
       const float* __restrict__ A, const float* __restrict__ B,
       float* __restrict__ C, const float* __restrict__ bias,
       int M, int N, int K, int lda, int ldb, int ldc, int act)
{
  __shared__ float As[16][64];
  __shared__ float Bs[16][64];
  int m0 = blockIdx.y*64, n0 = blockIdx.x*64;
  int t = threadIdx.x, tx = t & 15, ty = t >> 4;
  float acc[4][4] = {};
  int arow = t >> 2, akq = (t & 3) * 4;
  for (int k0 = 0; k0 < K; k0 += 16){
    float4 av = *(const float4*)(A + (size_t)(m0+arow)*lda + k0 + akq);
    As[akq+0][arow] = av.x; As[akq+1][arow] = av.y;
    As[akq+2][arow] = av.z; As[akq+3][arow] = av.w;
    float4 bv = make_float4(0.f,0.f,0.f,0.f);
    if (n0 + arow < N) bv = *(const float4*)(B + (size_t)(n0+arow)*ldb + k0 + akq);
    Bs[akq+0][arow]=bv.x; Bs[akq+1][arow]=bv.y;
    Bs[akq+2][arow]=bv.z; Bs[akq+3][arow]=bv.w;
    __syncthreads();
    #pragma unroll
    for (int k = 0; k < 16; ++k){
      float4 a = *(const float4*)&As[k][ty*4];
      float4 b = *(const float4*)&Bs[k][tx*4];
      acc[0][0] = fmaf(a.x,b.x,acc[0][0]); acc[0][1] = fmaf(a.x,b.y,acc[0][1]);
      acc[0][2] = fmaf(a.x,b.z,acc[0][2]); acc[0][3] = fmaf(a.x,b.w,acc[0][3]);
      acc[1][0] = fmaf(a.y,b.x,acc[1][0]); acc[1][1] = fmaf(a.y,b.y,acc[1][1]);
      acc[1][2] = fmaf(a.y,b.z,acc[1][2]); acc[1][3] = fmaf(a.y,b.w,acc[1][3]);
      acc[2][0] = fmaf(a.z,b.x,acc[2][0]); acc[2][1] = fmaf(a.z,b.y,acc[2][1]);
      acc[2][2] = fmaf(a.z,b.z,acc[2][2]); acc[2][3] = fmaf(a.z,b.w,acc[2][3]);
      acc[3][0] = fmaf(a.w,b.x,acc[3][0]); acc[3][1] = fmaf(a.w,b.y,acc[3][1]);
      acc[3][2] = fmaf(a.w,b.z,acc[3][2]); acc[3][3] = fmaf(a.w,b.w,acc[3][3]);
    }
    __syncthreads();
  }
  #pragma unroll
  for (int i = 0; i < 4; ++i){
    int m = m0 + ty*4 + i;
    #pragma unroll
    for (int j = 0; j < 4; ++j){
      int n = n0 + tx*4 + j;
      if (n < N){
        float v = acc[i][j];
        if (bias) v += bias[n];
        if (act == 1) v = sigf(v);
        else if (act == 2) v = softplusf(v);
        C[(size_t)m*ldc + n] = v;
      }
    }
  }
}

// ---------------- im2col for gate conv (K=3, pad 1) ----------------
__global__ void k_im2col(const float* __restrict__ seq, float* __restrict__ A2){
  int idx = blockIdx.x*256 + threadIdx.x;          // B*L*768
  int j  = idx % 768;
  int bl = idx / 768;
  int kk = j >> 8, c = j & 255;
  int l = bl & 1023, b = bl >> 10;
  int ls = l + kk - 1;
  float v = 0.f;
  if (ls >= 0 && ls < Ll) v = seq[(size_t)(b*Ll + ls)*C2 + c];
  A2[idx] = v;
}

// gate_w (O,I,3) -> W2 (O, kk*256+i)
__global__ void k_packw(const float* __restrict__ gw, float* __restrict__ W2){
  int idx = blockIdx.x*256 + threadIdx.x;          // 256*768
  int j = idx % 768, o = idx / 768;
  int kk = j >> 8, i = j & 255;
  W2[idx] = gw[(size_t)(o*256 + i)*3 + kk];
}

// ---------------- depthwise causal conv (KC=4) + SiLU ----------------
__global__ void k_dwconv(const float* __restrict__ xz, const float* __restrict__ cw,
                         const float* __restrict__ cb, float* __restrict__ xs){
  int idx = blockIdx.x*256 + threadIdx.x;          // B*L*512
  int d = idx & 511; int bl = idx >> 9; int l = bl & 1023; int b = bl >> 10;
  float s = cb[d];
  #pragma unroll
  for (int kk = 0; kk < 4; ++kk){
    int ls = l - 3 + kk;
    if (ls >= 0) s = fmaf(cw[d*4+kk], xz[(size_t)(b*Ll+ls)*1024 + d], s);
  }
  xs[idx] = s * sigf(s);
}

// ---------------- pre-scan: dtT/dtuT (time-major), replaces dt GEMM -------------
__global__ void k_pret(const float* __restrict__ xdbl, const float* __restrict__ xs,
                       const float* __restrict__ W_dt, const float* __restrict__ b_dt,
                       float* __restrict__ dtT, float* __restrict__ dtuT){
  __shared__ float X[32][17];    // xdbl[l][r]
  __shared__ float Wd[32][17];   // W_dt[d][r]
  __shared__ float xsb[32][33];  // xs[l][d]
  int b = blockIdx.z, d0 = blockIdx.y*32, l0 = blockIdx.x*32;
  int tx = threadIdx.x, ty = threadIdx.y;           // 32 x 8
  for (int i = ty; i < 32; i += 8){
    if (tx < 16)      X[i][tx]      = xdbl[(size_t)(b*Ll + l0 + i)*144 + tx];
    else              Wd[i][tx-16]  = W_dt[(size_t)(d0 + i)*16 + tx - 16];
    xsb[i][tx] = xs[(size_t)(b*Ll + l0 + i)*512 + d0 + tx];
  }
  __syncthreads();
  for (int dy = ty; dy < 32; dy += 8){
    int d = d0 + dy;
    float v = b_dt[d];
    #pragma unroll
    for (int r = 0; r < 16; ++r) v = fmaf(Wd[dy][r], X[tx][r], v);
    float dt = softplusf(v);
    size_t o = ((size_t)(b*512 + d))*Ll + l0 + tx;
    dtT[o]  = dt;
    dtuT[o] = dt * xsb[tx][dy];
  }
}

// ---------------- selective scan v5: 4 waves/block, shared B/C staging ----------
// Wave w scans channel d = grp*4 + w of batch b; B/C rows (identical for all d of
// a batch) staged ONCE per block by all 256 threads. 512 blocks -> all resident
// (r8: 2048 single-wave blocks = tail pass + lone-wave latency exposure).
__global__ void __launch_bounds__(256) k_scan5(
    const float* __restrict__ dtT, const float* __restrict__ dtuT,
    const float* __restrict__ xdbl, const float* __restrict__ A_log,
    float* __restrict__ yT){
  __shared__ float Bs[32*64];
  __shared__ float Cs[32*64];
  __shared__ float pb[4*32*65];
  int t = threadIdx.x;
  int w = t >> 6, lane = t & 63;
  int blk = blockIdx.x;                   // 0..511
  int b = blk >> 7, grp = blk & 127;
  int d = grp*4 + w;
  float Ac = -__expf(A_log[d*64 + lane]); // lane = state n
  float h = 0.f;
  size_t base = (size_t)b*Ll;
  size_t bd   = ((size_t)(b*512 + d))*Ll;
  int jl = lane & 31;
  bool lo = lane < 32;
  float* pbw = &pb[w*2080];
  for (int c0 = 0; c0 < Ll; c0 += 32){
    float dtv = 0.f, duv = 0.f;
    if (lo){
      dtv = dtT[bd + c0 + lane];          // lane j (<32) holds step c0+j
      duv = dtuT[bd + c0 + lane];
    }
    // cooperative staging: 256 threads cover 32 rows x 64 states, both arrays
    #pragma unroll
    for (int kk = 0; kk < 8; ++kk){
      int i = t + kk*256;                 // 0..2047
      int row = i >> 6, col = i & 63;
      size_t r2 = (base + c0 + row)*144;
      Bs[i] = xdbl[r2 + 16 + col];
      Cs[i] = xdbl[r2 + 80 + col];
    }
    __syncthreads();
    #pragma unroll
    for (int l = 0; l < 32; ++l){
      float sdt = __shfl(dtv, l);
      float sdu = __shfl(duv, l);
      float dA = __expf(sdt*Ac);
      h = fmaf(dA, h, sdu*Bs[l*64 + lane]);
      pbw[l*65 + lane] = h*Cs[l*64 + lane];
    }
    __syncthreads();
    {
      const float* rp = &pbw[jl*65 + (lo ? 0 : 32)];
      float s0=0.f, s1=0.f, s2=0.f, s3=0.f;
      #pragma unroll
      for (int n = 0; n < 32; n += 4){
        s0 += rp[n]; s1 += rp[n+1]; s2 += rp[n+2]; s3 += rp[n+3];
      }
      float p = (s0+s1)+(s2+s3);
      p += __shfl_xor(p, 32);
      if (lo) yT[bd + c0 + jl] = p;
    }
    __syncthreads();
  }
}

// ---------------- yT -> y transpose + scan epilogue fusion ----------------------
__global__ void k_ytrans(const float* __restrict__ yT, const float* __restrict__ xs,
                         const float* __restrict__ xz, const float* __restrict__ D_p,
                         float* __restrict__ y){
  __shared__ float t[32][33];
  int b = blockIdx.z, d0 = blockIdx.y*32, l0 = blockIdx.x*32;
  int tx = threadIdx.x, ty = threadIdx.y;
  for (int i = ty; i < 32; i += 8)
    t[i][tx] = yT[((size_t)(b*512 + d0 + i))*Ll + l0 + tx];
  __syncthreads();
  for (int i = ty; i < 32; i += 8){
    int d = d0 + tx;
    size_t bl = (size_t)b*Ll + l0 + i;
    float p  = t[tx][i];
    float u  = xs[bl*512 + d];
    float zv = xz[bl*1024 + 512 + d];
    y[bl*512 + d] = (p + D_p[d]*u) * (zv * sigf(zv));
  }
}

// ---------------- pack attention A/B operands (K=128 fold) ----------------
__global__ void k_pack_ab(const float* __restrict__ qt, const float* __restrict__ kt,
                          const float* __restrict__ rhm, const float* __restrict__ rwm,
                          float* __restrict__ Ab, float* __restrict__ Bb){
  int idx = blockIdx.x*256 + threadIdx.x;          // B*H*L*128
  int dd = idx & 127;
  int i  = (idx >> 7) & 1023;
  int h  = (idx >> 17) & 3;
  int b  = idx >> 19;
  float av, bv;
  if (dd < 64){
    size_t q = (size_t)(b*Ll + i)*C2 + h*64 + dd;
    av = qt[q]; bv = kt[q];
  } else {
    int d = dd - 64;
    av = rhm[(h*64+d)*32 + (i & 31)] + rwm[(h*64+d)*32 + (i >> 5)];
    bv = qt[(size_t)(b*Ll + i)*C2 + h*64 + d];
  }
  Ab[idx] = av; Bb[idx] = bv;
}

// ---------------- V transpose: vt (B*L,256) -> vT (B,256,L) ----------------
__global__ void k_vtrans(const float* __restrict__ vt, float* __restrict__ vT){
  __shared__ float t[32][33];
  int b = blockIdx.z, c0 = blockIdx.y*32, j0 = blockIdx.x*32;
  for (int i = threadIdx.y; i < 32; i += 8)
    t[i][threadIdx.x] = vt[(size_t)(b*Ll + j0 + i)*C2 + c0 + threadIdx.x];
  __syncthreads();
  for (int i = threadIdx.y; i < 32; i += 8)
    vT[((size_t)(b*C2 + c0 + i))*Ll + j0 + threadIdx.x] = t[threadIdx.x][i];
}

// ---------------- row softmax over 1024 (in place) ----------------
__global__ void __launch_bounds__(256) k_softmax(float* __restrict__ e){
  __shared__ float red[4];
  __shared__ float red2[4];
  size_t row = blockIdx.x;
  float* p = e + row*1024;
  int t = threadIdx.x;
  float v0 = p[t], v1 = p[t+256], v2 = p[t+512], v3 = p[t+768];
  float mx = fmaxf(fmaxf(v0,v1), fmaxf(v2,v3));
  #pragma unroll
  for (int off=32; off; off>>=1) mx = fmaxf(mx, __shfl_xor(mx, off));
  if ((t&63)==0) red[t>>6] = mx;
  __syncthreads();
  mx = fmaxf(fmaxf(red[0],red[1]), fmaxf(red[2],red[3]));
  v0 = __expf(v0-mx); v1 = __expf(v1-mx); v2 = __expf(v2-mx); v3 = __expf(v3-mx);
  float s = v0+v1+v2+v3;
  #pragma unroll
  for (int off=32; off; off>>=1) s += __shfl_xor(s, off);
  if ((t&63)==0) red2[t>>6] = s;
  __syncthreads();
  s = red2[0]+red2[1]+red2[2]+red2[3];
  float inv = 1.0f/s;
  p[t] = v0*inv; p[t+256] = v1*inv; p[t+512] = v2*inv; p[t+768] = v3*inv;
}

// ---------------- fused ym*ctx + reference's reshape-reinterpret ----------------
__global__ void k_mulshuf(const float* __restrict__ ym, const float* __restrict__ ctx,
                          float* __restrict__ out1t){
  __shared__ float t[32][33];
  int b = blockIdx.z >> 2, s1 = blockIdx.z & 3;
  int c0 = blockIdx.y*32, s00 = blockIdx.x*32;
  for (int i = threadIdx.y; i < 32; i += 8){
    int c = c0 + i;
    int l = c*4 + s1;
    size_t off = ((size_t)(b*Ll + l))*C2 + s00 + threadIdx.x;
    t[i][threadIdx.x] = ym[off] * ctx[off];
  }
  __syncthreads();
  for (int i = threadIdx.y; i < 32; i += 8){
    int s0 = s00 + i, c = c0 + threadIdx.x;
    int s = s1*256 + s0;
    out1t[((size_t)(b*Ll + s))*C2 + c] = t[threadIdx.x][i];
  }
}

// ---------------- scalar gates ga/gb ----------------
__global__ void __launch_bounds__(256) k_gates(
    const float* __restrict__ ap, const float* __restrict__ bp,
    const float* __restrict__ Wg, const float* __restrict__ bg, float* __restrict__ g){
  __shared__ float ra[4], rb[4];
  int bl = blockIdx.x; int t = threadIdx.x;
  float sa = 0.f, sb = 0.f;
  const float* a = ap + (size_t)bl*512;
  const float* bq = bp + (size_t)bl*512;
  for (int pp = t; pp < 512; pp += 256){ float w = Wg[pp]; sa = fmaf(w, a[pp], sa); sb = fmaf(w, bq[pp], sb); }
  #pragma unroll
  for (int off=32; off; off>>=1){ sa += __shfl_xor(sa,off); sb += __shfl_xor(sb,off); }
  if ((t&63)==0){ ra[t>>6]=sa; rb[t>>6]=sb; }
  __syncthreads();
  if (t==0){
    float b0 = bg[0];
    g[bl]        = sigf(ra[0]+ra[1]+ra[2]+ra[3] + b0);
    g[4096 + bl] = sigf(rb[0]+rb[1]+rb[2]+rb[3] + b0);
  }
}

// ---------------- final gated combine, transposed write ----------------
__global__ void k_final(const float* __restrict__ ap, const float* __restrict__ bp,
                        const float* __restrict__ g, float* __restrict__ out){
  int bpid = blockIdx.x; int b = bpid >> 9, p = bpid & 511;
  for (int l = threadIdx.x; l < Ll; l += 256){
    int bl = b*Ll + l;
    float ga = g[bl], gb = g[4096 + bl];
    out[((size_t)(b*Pp + p) << 10) + l] =
        ga*ap[(size_t)bl*512 + p] + gb*bp[(size_t)bl*512 + p];
  }
}

// ---------------- host side ----------------
static inline void mgemm(hipStream_t s, const float* A, const float* B, float* C,
                         const float* bias, int M, int N, int K, int lda, int ldb, int ldc,
                         int act){
  dim3 g(N/64, M/64, 1), blk(256);
  k_mgemmb<<<g, blk, 0, s>>>(A,B,C,bias,M,N,K,lda,ldb,ldc, 0,0,0,0,0,0, act);
}

extern "C" void kernel_launch(void* const* d_in, const int* in_sizes, int n_in,
                              void* d_out, int out_size, void* d_ws, size_t ws_size,
                              hipStream_t stream) {
  const float* x      = (const float*)d_in[0];
  const float* rh_c   = (const float*)d_in[1];
  const float* rw_c   = (const float*)d_in[2];
  const float* gate_w = (const float*)d_in[3];
  const float* gate_b = (const float*)d_in[4];
  const float* W_in   = (const float*)d_in[5];
  const float* conv_w = (const float*)d_in[6];
  const float* conv_b = (const float*)d_in[7];
  const float* W_x    = (const float*)d_in[8];
  const float* W_dt   = (const float*)d_in[9];
  const float* b_dt   = (const float*)d_in[10];
  const float* A_log  = (const float*)d_in[11];
  const float* D_p    = (const float*)d_in[12];
  const float* W_out  = (const float*)d_in[13];
  const float* Wq     = (const float*)d_in[14];
  const float* bq     = (const float*)d_in[15];
  const float* Wk     = (const float*)d_in[16];
  const float* bk     = (const float*)d_in[17];
  const float* Wv     = (const float*)d_in[18];
  const float* bv     = (const float*)d_in[19];
  const float* rhm    = (const float*)d_in[20];
  const float* rwm    = (const float*)d_in[21];
  // d_in[22] reg_qk, d_in[23] reg_v: provably dead (softmax per-head, head 4 discarded)
  const float* Wa     = (const float*)d_in[24];
  const float* ba     = (const float*)d_in[25];
  const float* Wb     = (const float*)d_in[26];
  const float* bb     = (const float*)d_in[27];
  const float* Wg     = (const float*)d_in[28];
  const float* bg     = (const float*)d_in[29];
  float* out = (float*)d_out;
  float* ws  = (float*)d_ws;

  // ws layout (floats). Total ≈ 131 MB.
  float* seq    = ws;                       // 1,048,576
  float* x2seq  = ws +  1048576;            // 1,048,576
  float* qt     = ws +  2097152;            // 1,048,576
  float* kt     = ws +  3145728;            // 1,048,576
  float* vt     = ws +  4194304;            // 1,048,576
  float* Abuf   = ws +  5242880;            // 2,097,152 (mamba: dtT)
  float* Bbuf   = ws +  7340032;            // 2,097,152 (mamba: dtuT)
  float* arena  = ws +  9437184;            // 16,777,216 (energy OR mamba chain)
  float* out2   = ws + 26214400;            // 1,048,576
  float* out1   = ws + 27262976;            // 1,048,576
  float* aproj  = ws + 28311552;            // 2,097,152 (vT parks here during attention)
  float* bproj  = ws + 30408704;            // 2,097,152
  float* gates  = ws + 32505856;            // 8,192
  float* W2     = ws + 32514048;            // 196,608
  // arena sub-layout (mamba phase):
  float* A2   = arena;                      // 3,145,728
  float* ctx  = arena +  3145728;           // 1,048,576
  float* xz   = arena +  4194304;           // 4,194,304
  float* xs   = arena +  8388608;           // 2,097,152
  float* xdbl = arena + 10485760;           // 589,824
  float* yT   = arena + 11075584;           // 2,097,152
  float* yb   = arena + 13172736;           // 2,097,152
  float* ym   = arena + 15269888;           // 1,048,576
  float* energy = arena;                    // 16,777,216 (attention phase)
  float* vT   = aproj;                      // 1,048,576 (attention phase only)
  float* dtT  = Abuf;                       // 2,097,152 (mamba phase only)
  float* dtuT = Bbuf;                       // 2,097,152 (mamba phase only)

  // 1. transpose x -> seq(+pos), x2seq
  k_transpose<<<dim3(32,16,4), dim3(32,8), 0, stream>>>(x, rh_c, rw_c, seq, x2seq);

  // ---- attention branch first (uses arena as energy) ----
  mgemm(stream, x2seq, Wq, qt, bq, 4096,256,256, 256,256,256, 0);
  mgemm(stream, x2seq, Wk, kt, bk, 4096,256,256, 256,256,256, 0);
  mgemm(stream, x2seq, Wv, vt, bv, 4096,256,256, 256,256,256, 0);
  k_pack_ab<<<8192, 256, 0, stream>>>(qt, kt, rhm, rwm, Abuf, Bbuf);
  k_vtrans<<<dim3(32,8,4), dim3(32,8), 0, stream>>>(vt, vT);
  // energy[z] = Abuf[z] @ Bbuf[z]^T  (M=N=1024, K=128), z = b*4+h  [128² tile]
  {
    dim3 g(8, 8, 16), blk(256);
    k_m128<<<g, blk, 0, stream>>>(Abuf, Bbuf, energy, nullptr,
        1024,1024,128, 128,128,1024,
        4L*131072, 131072, 4L*131072, 131072, 4L*1048576, 1048576, 0);
  }
  k_softmax<<<16384, 256, 0, stream>>>(energy);
  // PV via 64² kernel: out2[b,i,h*64+d] = sum_j attn[z][i,j] * vT[b, h*64+d, j]
  {
    dim3 g(1, 16, 16), blk(256);
    k_mgemmb<<<g, blk, 0, stream>>>(energy, vT, out2, nullptr,
        1024,64,1024, 1024,1024,256,
        4L*1048576, 1048576, 262144, 65536, 262144, 64, 0);
  }

  // ---- mamba branch (arena reused; Abuf/Bbuf/vT free after PV) ----
  k_packw<<<768, 256, 0, stream>>>(gate_w, W2);
  k_im2col<<<12288, 256, 0, stream>>>(seq, A2);
  mgemm(stream, A2, W2, ctx, gate_b, 4096,256,768, 768,768,256, 1);
  // xz = seq @ W_in^T   [128² tile]
  {
    dim3 g(8, 32, 1), blk(256);
    k_m128<<<g, blk, 0, stream>>>(seq, W_in, xz, nullptr,
        4096,1024,256, 256,256,1024, 0,0,0,0,0,0, 0);
  }
  k_dwconv<<<8192, 256, 0, stream>>>(xz, conv_w, conv_b, xs);
  // x_dbl = xs @ W_x^T   (N=144 -> fp32 guarded path)
  {
    dim3 g(3, 64, 1), blk(256);
    k_gemm<<<g, blk, 0, stream>>>(xs, W_x, xdbl, nullptr, 4096,144,512, 512,512,144, 0);
  }
  k_pret<<<dim3(32,16,4), dim3(32,8), 0, stream>>>(xdbl, xs, W_dt, b_dt, dtT, dtuT);
  // selective scan v5 (4 waves/block, shared staging)
  k_scan5<<<512, 256, 0, stream>>>(dtT, dtuT, xdbl, A_log, yT);
  k_ytrans<<<dim3(32,16,4), dim3(32,8), 0, stream>>>(yT, xs, xz, D_p, yb);
  mgemm(stream, yb, W_out, ym, nullptr, 4096,256,512, 512,512,256, 0);
  k_mulshuf<<<dim3(8,8,16), dim3(32,8), 0, stream>>>(ym, ctx, out1);

  // ---- fusion head ----
  mgemm(stream, out1, Wa, aproj, ba, 4096,512,256, 256,256,512, 0);
  mgemm(stream, out2, Wb, bproj, bb, 4096,512,256, 256,256,512, 0);
  k_gates<<<4096, 256, 0, stream>>>(aproj, bproj, Wg, bg, gates);
  k_final<<<2048, 256, 0, stream>>>(aproj, bproj, gates, out);
}

// Round 10
// 565.256 us; speedup vs baseline: 1.1414x; 1.0179x over previous
//
#include <hip/hip_runtime.h>
#include <math.h>

// Problem constants
static constexpr int Bn = 4, Pp = 512, C2 = 256, HEAD = 4, DHd = 64;
static constexpr int Ll = 1024, DIi = 512, Nn = 64, Rr = 16, KCc = 4;
static constexpr int XDW = 192;   // padded xdbl row stride (was 144)

#define DEVI __device__ __forceinline__

DEVI float sigf(float x){ return 1.0f/(1.0f+__expf(-x)); }
DEVI float softplusf(float x){ return x > 20.f ? x : log1pf(__expf(x)); }

// bf16 split helpers (RNE hi, exact residual -> RNE lo)
DEVI unsigned short bfh(float f){
  unsigned int u = __float_as_uint(f);
  return (unsigned short)((u + 0x7FFFu + ((u>>16)&1u)) >> 16);
}
DEVI float bff(unsigned short h){ return __uint_as_float(((unsigned int)h)<<16); }

typedef __attribute__((ext_vector_type(8))) short  bf8v;   // 8 bf16 in 4 VGPRs
typedef __attribute__((ext_vector_type(4))) float  f4v;
typedef __attribute__((ext_vector_type(8))) unsigned short u16x8;

// ---------------- transpose x -> seq (+pos), x2seq ----------------
__global__ void k_transpose(const float* __restrict__ x, const float* __restrict__ rh,
                            const float* __restrict__ rw, float* __restrict__ seq,
                            float* __restrict__ x2seq){
  __shared__ float t[32][33];
  int b = blockIdx.z, c0 = blockIdx.y*32, l0 = blockIdx.x*32;
  for (int i = threadIdx.y; i < 32; i += 8)
    t[i][threadIdx.x] = x[((size_t)(b*Pp + c0 + i)*Ll) + l0 + threadIdx.x];
  __syncthreads();
  for (int i = threadIdx.y; i < 32; i += 8){
    int l = l0 + i, c = c0 + threadIdx.x;
    float v = t[threadIdx.x][i];
    if (c < C2){
      float pos = rh[c*32 + (l & 31)] + rw[c*32 + (l >> 5)];
      seq[(size_t)(b*Ll + l)*C2 + c] = v + pos;
    } else {
      x2seq[(size_t)(b*Ll + l)*C2 + (c - C2)] = v;
    }
  }
}

// ---------------- split-bf16 MFMA GEMM, 64x64 tile (r6-r9 replay-proven) --------
// C[m,n] = act( sum_k A[m,k]*B[n,k] + bias[n] ),  B is (N,K) row-major.
// M%64==0, N%64==0, K%32==0. Batch z: base += (z>>2)*s?1 + (z&3)*s?2.
__global__ void __launch_bounds__(256) k_mgemmb(
    const float* __restrict__ A, const float* __restrict__ B,
    float* __restrict__ C, const float* __restrict__ bias,
    int M, int N, int K, int lda, int ldb, int ldc,
    long sA1, long sA2, long sB1, long sB2, long sC1, long sC2, int act)
{
  __shared__ __align__(16) unsigned short Ah[64*40], Al[64*40], Bh[64*40], Bl[64*40];
  int z = blockIdx.z;
  const float* Ab = A + (size_t)((z>>2)*sA1 + (z&3)*sA2);
  const float* Bb = B + (size_t)((z>>2)*sB1 + (z&3)*sB2);
  float*       Cb = C + (size_t)((z>>2)*sC1 + (z&3)*sC2);
  int m0 = blockIdx.y*64, n0 = blockIdx.x*64;
  int t = threadIdx.x;
  int w = t >> 6, l = t & 63;
  int g = l >> 4, r = l & 15;
  int row0 = w*16;

  f4v acc[4];
  #pragma unroll
  for (int j=0;j<4;++j) acc[j] = (f4v){0.f,0.f,0.f,0.f};

  int sr = t >> 2;            // 0..63
  int sc = (t & 3) * 8;       // 0,8,16,24

  for (int k0 = 0; k0 < K; k0 += 32){
    {
      const float* src = Ab + (size_t)(m0+sr)*lda + k0 + sc;
      float4 v0 = *(const float4*)(src);
      float4 v1 = *(const float4*)(src+4);
      float f[8] = {v0.x,v0.y,v0.z,v0.w,v1.x,v1.y,v1.z,v1.w};
      u16x8 hv, lv;
      #pragma unroll
      for (int i=0;i<8;++i){
        unsigned short h = bfh(f[i]); hv[i] = h;
        lv[i] = bfh(f[i] - bff(h));
      }
      *(u16x8*)&Ah[sr*40+sc] = hv;
      *(u16x8*)&Al[sr*40+sc] = lv;
    }
    {
      const float* src = Bb + (size_t)(n0+sr)*ldb + k0 + sc;
      float4 v0 = *(const float4*)(src);
      float4 v1 = *(const float4*)(src+4);
      float f[8] = {v0.x,v0.y,v0.z,v0.w,v1.x,v1.y,v1.z,v1.w};
      u16x8 hv, lv;
      #pragma unroll
      for (int i=0;i<8;++i){
        unsigned short h = bfh(f[i]); hv[i] = h;
        lv[i] = bfh(f[i] - bff(h));
      }
      *(u16x8*)&Bh[sr*40+sc] = hv;
      *(u16x8*)&Bl[sr*40+sc] = lv;
    }
    __syncthreads();
    bf8v a_h = *(const bf8v*)&Ah[(row0+r)*40 + g*8];
    bf8v a_l = *(const bf8v*)&Al[(row0+r)*40 + g*8];
    #pragma unroll
    for (int j=0;j<4;++j){
      bf8v b_h = *(const bf8v*)&Bh[(j*16+r)*40 + g*8];
      bf8v b_l = *(const bf8v*)&Bl[(j*16+r)*40 + g*8];
      acc[j] = __builtin_amdgcn_mfma_f32_16x16x32_bf16(a_h, b_h, acc[j], 0, 0, 0);
      acc[j] = __builtin_amdgcn_mfma_f32_16x16x32_bf16(a_h, b_l, acc[j], 0, 0, 0);
      acc[j] = __builtin_amdgcn_mfma_f32_16x16x32_bf16(a_l, b_h, acc[j], 0, 0, 0);
    }
    __syncthreads();
  }
  #pragma unroll
  for (int j=0;j<4;++j){
    int n = n0 + j*16 + r;
    float bv = bias ? bias[n] : 0.f;
    #pragma unroll
    for (int q=0;q<4;++q){
      int m = m0 + row0 + g*4 + q;
      float v = acc[j][q] + bv;
      if (act == 1) v = sigf(v);
      Cb[(size_t)m*ldc + n] = v;
    }
  }
}

// ---------------- split-bf16 MFMA GEMM, 128x128 tile (energy & xz) --------------
__global__ void __launch_bounds__(256) k_m128(
    const float* __restrict__ A, const float* __restrict__ B,
    float* __restrict__ C, const float* __restrict__ bias,
    int M, int N, int K, int lda, int ldb, int ldc,
    long sA1, long sA2, long sB1, long sB2, long sC1, long sC2, int act)
{
  __shared__ __align__(16) unsigned short Ah[128*40], Al[128*40], Bh[128*40], Bl[128*40];
  int z = blockIdx.z;
  const float* Ab = A + (size_t)((z>>2)*sA1 + (z&3)*sA2);
  const float* Bb = B + (size_t)((z>>2)*sB1 + (z&3)*sB2);
  float*       Cb = C + (size_t)((z>>2)*sC1 + (z&3)*sC2);
  int m0 = blockIdx.y*128, n0 = blockIdx.x*128;
  int t = threadIdx.x;
  int w = t >> 6, l = t & 63;
  int g = l >> 4, r = l & 15;
  int row0 = w*32;

  f4v acc[2][8];
  #pragma unroll
  for (int i=0;i<2;++i)
    #pragma unroll
    for (int j=0;j<8;++j) acc[i][j] = (f4v){0.f,0.f,0.f,0.f};

  int sr = t >> 1;            // 0..127
  int sc = (t & 1) * 16;      // 0,16

  for (int k0 = 0; k0 < K; k0 += 32){
    {
      const float* src = Ab + (size_t)(m0+sr)*lda + k0 + sc;
      float4 v0 = *(const float4*)(src);
      float4 v1 = *(const float4*)(src+4);
      float4 v2 = *(const float4*)(src+8);
      float4 v3 = *(const float4*)(src+12);
      float f[16] = {v0.x,v0.y,v0.z,v0.w,v1.x,v1.y,v1.z,v1.w,
                     v2.x,v2.y,v2.z,v2.w,v3.x,v3.y,v3.z,v3.w};
      u16x8 hv0, lv0, hv1, lv1;
      #pragma unroll
      for (int i=0;i<8;++i){
        unsigned short h = bfh(f[i]); hv0[i] = h;
        lv0[i] = bfh(f[i] - bff(h));
      }
      #pragma unroll
      for (int i=0;i<8;++i){
        unsigned short h = bfh(f[8+i]); hv1[i] = h;
        lv1[i] = bfh(f[8+i] - bff(h));
      }
      *(u16x8*)&Ah[sr*40+sc]   = hv0;  *(u16x8*)&Ah[sr*40+sc+8] = hv1;
      *(u16x8*)&Al[sr*40+sc]   = lv0;  *(u16x8*)&Al[sr*40+sc+8] = lv1;
    }
    {
      const float* src = Bb + (size_t)(n0+sr)*ldb + k0 + sc;
      float4 v0 = *(const float4*)(src);
      float4 v1 = *(const float4*)(src+4);
      float4 v2 = *(const float4*)(src+8);
      float4 v3 = *(const float4*)(src+12);
      float f[16] = {v0.x,v0.y,v0.z,v0.w,v1.x,v1.y,v1.z,v1.w,
                     v2.x,v2.y,v2.z,v2.w,v3.x,v3.y,v3.z,v3.w};
      u16x8 hv0, lv0, hv1, lv1;
      #pragma unroll
      for (int i=0;i<8;++i){
        unsigned short h = bfh(f[i]); hv0[i] = h;
        lv0[i] = bfh(f[i] - bff(h));
      }
      #pragma unroll
      for (int i=0;i<8;++i){
        unsigned short h = bfh(f[8+i]); hv1[i] = h;
        lv1[i] = bfh(f[8+i] - bff(h));
      }
      *(u16x8*)&Bh[sr*40+sc]   = hv0;  *(u16x8*)&Bh[sr*40+sc+8] = hv1;
      *(u16x8*)&Bl[sr*40+sc]   = lv0;  *(u16x8*)&Bl[sr*40+sc+8] = lv1;
    }
    __syncthreads();
    bf8v a_h0 = *(const bf8v*)&Ah[(row0+r)*40 + g*8];
    bf8v a_l0 = *(const bf8v*)&Al[(row0+r)*40 + g*8];
    bf8v a_h1 = *(const bf8v*)&Ah[(row0+16+r)*40 + g*8];
    bf8v a_l1 = *(const bf8v*)&Al[(row0+16+r)*40 + g*8];
    #pragma unroll
    for (int j=0;j<8;++j){
      bf8v b_h = *(const bf8v*)&Bh[(j*16+r)*40 + g*8];
      bf8v b_l = *(const bf8v*)&Bl[(j*16+r)*40 + g*8];
      acc[0][j] = __builtin_amdgcn_mfma_f32_16x16x32_bf16(a_h0, b_h, acc[0][j], 0, 0, 0);
      acc[0][j] = __builtin_amdgcn_mfma_f32_16x16x32_bf16(a_h0, b_l, acc[0][j], 0, 0, 0);
      acc[0][j] = __builtin_amdgcn_mfma_f32_16x16x32_bf16(a_l0, b_h, acc[0][j], 0, 0, 0);
      acc[1][j] = __builtin_amdgcn_mfma_f32_16x16x32_bf16(a_h1, b_h, acc[1][j], 0, 0, 0);
      acc[1][j] = __builtin_amdgcn_mfma_f32_16x16x32_bf16(a_h1, b_l, acc[1][j], 0, 0, 0);
      acc[1][j] = __builtin_amdgcn_mfma_f32_16x16x32_bf16(a_l1, b_h, acc[1][j], 0, 0, 0);
    }
    __syncthreads();
  }
  #pragma unroll
  for (int i=0;i<2;++i){
    #pragma unroll
    for (int j=0;j<8;++j){
      int n = n0 + j*16 + r;
      float bv = bias ? bias[n] : 0.f;
      #pragma unroll
      for (int q=0;q<4;++q){
        int m = m0 + row0 + i*16 + g*4 + q;
        float v = acc[i][j][q] + bv;
        if (act == 1) v = sigf(v);
        Cb[(size_t)m*ldc + n] = v;
      }
    }
  }
}

// ---------------- pad W_x (144x512) -> W_xp (192x512, zero-filled) ----------------
__global__ void k_padwx(const float* __restrict__ W_x, float* __restrict__ W_xp){
  int idx = blockIdx.x*256 + threadIdx.x;          // 192*512
  int row = idx >> 9;
  W_xp[idx] = (row < 144) ? W_x[(size_t)(row)*512 + (idx & 511)] : 0.f;
}

// ---------------- im2col for gate conv (K=3, pad 1) ----------------
__global__ void k_im2col(const float* __restrict__ seq, float* __restrict__ A2){
  int idx = blockIdx.x*256 + threadIdx.x;          // B*L*768
  int j  = idx % 768;
  int bl = idx / 768;
  int kk = j >> 8, c = j & 255;
  int l = bl & 1023, b = bl >> 10;
  int ls = l + kk - 1;
  float v = 0.f;
  if (ls >= 0 && ls < Ll) v = seq[(size_t)(b*Ll + ls)*C2 + c];
  A2[idx] = v;
}

// gate_w (O,I,3) -> W2 (O, kk*256+i)
__global__ void k_packw(const float* __restrict__ gw, float* __restrict__ W2){
  int idx = blockIdx.x*256 + threadIdx.x;          // 256*768
  int j = idx % 768, o = idx / 768;
  int kk = j >> 8, i = j & 255;
  W2[idx] = gw[(size_t)(o*256 + i)*3 + kk];
}

// ---------------- depthwise causal conv (KC=4) + SiLU ----------------
__global__ void k_dwconv(const float* __restrict__ xz, const float* __restrict__ cw,
                         const float* __restrict__ cb, float* __restrict__ xs){
  int idx = blockIdx.x*256 + threadIdx.x;          // B*L*512
  int d = idx & 511; int bl = idx >> 9; int l = bl & 1023; int b = bl >> 10;
  float s = cb[d];
  #pragma unroll
  for (int kk = 0; kk < 4; ++kk){
    int ls = l - 3 + kk;
    if (ls >= 0) s = fmaf(cw[d*4+kk], xz[(size_t)(b*Ll+ls)*1024 + d], s);
  }
  xs[idx] = s * sigf(s);
}

// ---------------- pre-scan: dtT/dtuT (time-major), from padded xdbl -------------
__global__ void k_pret(const float* __restrict__ xdbl, const float* __restrict__ xs,
                       const float* __restrict__ W_dt, const float* __restrict__ b_dt,
                       float* __restrict__ dtT, float* __restrict__ dtuT){
  __shared__ float X[32][17];    // xdbl[l][r]
  __shared__ float Wd[32][17];   // W_dt[d][r]
  __shared__ float xsb[32][33];  // xs[l][d]
  int b = blockIdx.z, d0 = blockIdx.y*32, l0 = blockIdx.x*32;
  int tx = threadIdx.x, ty = threadIdx.y;           // 32 x 8
  for (int i = ty; i < 32; i += 8){
    if (tx < 16)      X[i][tx]      = xdbl[(size_t)(b*Ll + l0 + i)*XDW + tx];
    else              Wd[i][tx-16]  = W_dt[(size_t)(d0 + i)*16 + tx - 16];
    xsb[i][tx] = xs[(size_t)(b*Ll + l0 + i)*512 + d0 + tx];
  }
  __syncthreads();
  for (int dy = ty; dy < 32; dy += 8){
    int d = d0 + dy;
    float v = b_dt[d];
    #pragma unroll
    for (int r = 0; r < 16; ++r) v = fmaf(Wd[dy][r], X[tx][r], v);
    float dt = softplusf(v);
    size_t o = ((size_t)(b*512 + d))*Ll + l0 + tx;
    dtT[o]  = dt;
    dtuT[o] = dt * xsb[tx][dy];
  }
}

// ---------------- selective scan v6: hand-pipelined serial phase ----------------
// v5 structure (4 waves/block, shared B/C staging) + the per-step exp/shfl/B-mul
// hoisted into statically-indexed register arrays BEFORE the serial loop, so the
// true serial chain is 32 chained FMAs per chunk (r9: ~250 cy/step, chain is only
// the h-FMA; exp & operands are h-independent). launch_bounds(256,1): no VGPR cap.
__global__ void __launch_bounds__(256, 1) k_scan6(
    const float* __restrict__ dtT, const float* __restrict__ dtuT,
    const float* __restrict__ xdbl, const float* __restrict__ A_log,
    float* __restrict__ yT){
  __shared__ float Bs[32*64];
  __shared__ float Cs[32*64];
  __shared__ float pb[4*32*65];
  int t = threadIdx.x;
  int w = t >> 6, lane = t & 63;
  int blk = blockIdx.x;                   // 0..511
  int b = blk >> 7, grp = blk & 127;
  int d = grp*4 + w;
  float Ac = -__expf(A_log[d*64 + lane]); // lane = state n
  float h = 0.f;
  size_t base = (size_t)b*Ll;
  size_t bd   = ((size_t)(b*512 + d))*Ll;
  int jl = lane & 31;
  bool lo = lane < 32;
  float* pbw = &pb[w*2080];
  for (int c0 = 0; c0 < Ll; c0 += 32){
    float dtv = 0.f, duv = 0.f;
    if (lo){
      dtv = dtT[bd + c0 + lane];          // lane j (<32) holds step c0+j
      duv = dtuT[bd + c0 + lane];
    }
    // cooperative staging: 256 threads cover 32 rows x 64 states, both arrays
    #pragma unroll
    for (int kk = 0; kk < 8; ++kk){
      int i = t + kk*256;                 // 0..2047
      int row = i >> 6, col = i & 63;
      size_t r2 = (base + c0 + row)*XDW;
      Bs[i] = xdbl[r2 + 16 + col];
      Cs[i] = xdbl[r2 + 80 + col];
    }
    __syncthreads();
    // phase A: precompute everything h-independent (static register arrays)
    float ev[32], gv[32];
    #pragma unroll
    for (int l = 0; l < 32; ++l){
      float sdt = __shfl(dtv, l);
      float sdu = __shfl(duv, l);
      ev[l] = __expf(sdt*Ac);
      gv[l] = sdu*Bs[l*64 + lane];
    }
    // phase B: serial chain = 32 chained FMAs; LDS write is off-chain
    #pragma unroll
    for (int l = 0; l < 32; ++l){
      h = fmaf(ev[l], h, gv[l]);
      pbw[l*65 + lane] = h*Cs[l*64 + lane];
    }
    __syncthreads();
    {
      const float* rp = &pbw[jl*65 + (lo ? 0 : 32)];
      float s0=0.f, s1=0.f, s2=0.f, s3=0.f;
      #pragma unroll
      for (int n = 0; n < 32; n += 4){
        s0 += rp[n]; s1 += rp[n+1]; s2 += rp[n+2]; s3 += rp[n+3];
      }
      float p = (s0+s1)+(s2+s3);
      p += __shfl_xor(p, 32);
      if (lo) yT[bd + c0 + jl] = p;
    }
    __syncthreads();
  }
}

// ---------------- yT -> y transpose + scan epilogue fusion ----------------------
__global__ void k_ytrans(const float* __restrict__ yT, const float* __restrict__ xs,
                         const float* __restrict__ xz, const float* __restrict__ D_p,
                         float* __restrict__ y){
  __shared__ float t[32][33];
  int b = blockIdx.z, d0 = blockIdx.y*32, l0 = blockIdx.x*32;
  int tx = threadIdx.x, ty = threadIdx.y;
  for (int i = ty; i < 32; i += 8)
    t[i][tx] = yT[((size_t)(b*512 + d0 + i))*Ll + l0 + tx];
  __syncthreads();
  for (int i = ty; i < 32; i += 8){
    int d = d0 + tx;
    size_t bl = (size_t)b*Ll + l0 + i;
    float p  = t[tx][i];
    float u  = xs[bl*512 + d];
    float zv = xz[bl*1024 + 512 + d];
    y[bl*512 + d] = (p + D_p[d]*u) * (zv * sigf(zv));
  }
}

// ---------------- pack attention A/B operands (K=128 fold) ----------------
__global__ void k_pack_ab(const float* __restrict__ qt, const float* __restrict__ kt,
                          const float* __restrict__ rhm, const float* __restrict__ rwm,
                          float* __restrict__ Ab, float* __restrict__ Bb){
  int idx = blockIdx.x*256 + threadIdx.x;          // B*H*L*128
  int dd = idx & 127;
  int i  = (idx >> 7) & 1023;
  int h  = (idx >> 17) & 3;
  int b  = idx >> 19;
  float av, bv;
  if (dd < 64){
    size_t q = (size_t)(b*Ll + i)*C2 + h*64 + dd;
    av = qt[q]; bv = kt[q];
  } else {
    int d = dd - 64;
    av = rhm[(h*64+d)*32 + (i & 31)] + rwm[(h*64+d)*32 + (i >> 5)];
    bv = qt[(size_t)(b*Ll + i)*C2 + h*64 + d];
  }
  Ab[idx] = av; Bb[idx] = bv;
}

// ---------------- V transpose: vt (B*L,256) -> vT (B,256,L) ----------------
__global__ void k_vtrans(const float* __restrict__ vt, float* __restrict__ vT){
  __shared__ float t[32][33];
  int b = blockIdx.z, c0 = blockIdx.y*32, j0 = blockIdx.x*32;
  for (int i = threadIdx.y; i < 32; i += 8)
    t[i][threadIdx.x] = vt[(size_t)(b*Ll + j0 + i)*C2 + c0 + threadIdx.x];
  __syncthreads();
  for (int i = threadIdx.y; i < 32; i += 8)
    vT[((size_t)(b*C2 + c0 + i))*Ll + j0 + threadIdx.x] = t[threadIdx.x][i];
}

// ---------------- row softmax over 1024 (in place) ----------------
__global__ void __launch_bounds__(256) k_softmax(float* __restrict__ e){
  __shared__ float red[4];
  __shared__ float red2[4];
  size_t row = blockIdx.x;
  float* p = e + row*1024;
  int t = threadIdx.x;
  float v0 = p[t], v1 = p[t+256], v2 = p[t+512], v3 = p[t+768];
  float mx = fmaxf(fmaxf(v0,v1), fmaxf(v2,v3));
  #pragma unroll
  for (int off=32; off; off>>=1) mx = fmaxf(mx, __shfl_xor(mx, off));
  if ((t&63)==0) red[t>>6] = mx;
  __syncthreads();
  mx = fmaxf(fmaxf(red[0],red[1]), fmaxf(red[2],red[3]));
  v0 = __expf(v0-mx); v1 = __expf(v1-mx); v2 = __expf(v2-mx); v3 = __expf(v3-mx);
  float s = v0+v1+v2+v3;
  #pragma unroll
  for (int off=32; off; off>>=1) s += __shfl_xor(s, off);
  if ((t&63)==0) red2[t>>6] = s;
  __syncthreads();
  s = red2[0]+red2[1]+red2[2]+red2[3];
  float inv = 1.0f/s;
  p[t] = v0*inv; p[t+256] = v1*inv; p[t+512] = v2*inv; p[t+768] = v3*inv;
}

// ---------------- fused ym*ctx + reference's reshape-reinterpret ----------------
__global__ void k_mulshuf(const float* __restrict__ ym, const float* __restrict__ ctx,
                          float* __restrict__ out1t){
  __shared__ float t[32][33];
  int b = blockIdx.z >> 2, s1 = blockIdx.z & 3;
  int c0 = blockIdx.y*32, s00 = blockIdx.x*32;
  for (int i = threadIdx.y; i < 32; i += 8){
    int c = c0 + i;
    int l = c*4 + s1;
    size_t off = ((size_t)(b*Ll + l))*C2 + s00 + threadIdx.x;
    t[i][threadIdx.x] = ym[off] * ctx[off];
  }
  __syncthreads();
  for (int i = threadIdx.y; i < 32; i += 8){
    int s0 = s00 + i, c = c0 + threadIdx.x;
    int s = s1*256 + s0;
    out1t[((size_t)(b*Ll + s))*C2 + c] = t[threadIdx.x][i];
  }
}

// ---------------- scalar gates ga/gb ----------------
__global__ void __launch_bounds__(256) k_gates(
    const float* __restrict__ ap, const float* __restrict__ bp,
    const float* __restrict__ Wg, const float* __restrict__ bg, float* __restrict__ g){
  __shared__ float ra[4], rb[4];
  int bl = blockIdx.x; int t = threadIdx.x;
  float sa = 0.f, sb = 0.f;
  const float* a = ap + (size_t)bl*512;
  const float* bq = bp + (size_t)bl*512;
  for (int pp = t; pp < 512; pp += 256){ float w = Wg[pp]; sa = fmaf(w, a[pp], sa); sb = fmaf(w, bq[pp], sb); }
  #pragma unroll
  for (int off=32; off; off>>=1){ sa += __shfl_xor(sa,off); sb += __shfl_xor(sb,off); }
  if ((t&63)==0){ ra[t>>6]=sa; rb[t>>6]=sb; }
  __syncthreads();
  if (t==0){
    float b0 = bg[0];
    g[bl]        = sigf(ra[0]+ra[1]+ra[2]+ra[3] + b0);
    g[4096 + bl] = sigf(rb[0]+rb[1]+rb[2]+rb[3] + b0);
  }
}

// ---------------- final gated combine, transposed write ----------------
__global__ void k_final(const float* __restrict__ ap, const float* __restrict__ bp,
                        const float* __restrict__ g, float* __restrict__ out){
  int bpid = blockIdx.x; int b = bpid >> 9, p = bpid & 511;
  for (int l = threadIdx.x; l < Ll; l += 256){
    int bl = b*Ll + l;
    float ga = g[bl], gb = g[4096 + bl];
    out[((size_t)(b*Pp + p) << 10) + l] =
        ga*ap[(size_t)bl*512 + p] + gb*bp[(size_t)bl*512 + p];
  }
}

// ---------------- host side ----------------
static inline void mgemm(hipStream_t s, const float* A, const float* B, float* C,
                         const float* bias, int M, int N, int K, int lda, int ldb, int ldc,
                         int act){
  dim3 g(N/64, M/64, 1), blk(256);
  k_mgemmb<<<g, blk, 0, s>>>(A,B,C,bias,M,N,K,lda,ldb,ldc, 0,0,0,0,0,0, act);
}

extern "C" void kernel_launch(void* const* d_in, const int* in_sizes, int n_in,
                              void* d_out, int out_size, void* d_ws, size_t ws_size,
                              hipStream_t stream) {
  const float* x      = (const float*)d_in[0];
  const float* rh_c   = (const float*)d_in[1];
  const float* rw_c   = (const float*)d_in[2];
  const float* gate_w = (const float*)d_in[3];
  const float* gate_b = (const float*)d_in[4];
  const float* W_in   = (const float*)d_in[5];
  const float* conv_w = (const float*)d_in[6];
  const float* conv_b = (const float*)d_in[7];
  const float* W_x    = (const float*)d_in[8];
  const float* W_dt   = (const float*)d_in[9];
  const float* b_dt   = (const float*)d_in[10];
  const float* A_log  = (const float*)d_in[11];
  const float* D_p    = (const float*)d_in[12];
  const float* W_out  = (const float*)d_in[13];
  const float* Wq     = (const float*)d_in[14];
  const float* bq     = (const float*)d_in[15];
  const float* Wk     = (const float*)d_in[16];
  const float* bk     = (const float*)d_in[17];
  const float* Wv     = (const float*)d_in[18];
  const float* bv     = (const float*)d_in[19];
  const float* rhm    = (const float*)d_in[20];
  const float* rwm    = (const float*)d_in[21];
  // d_in[22] reg_qk, d_in[23] reg_v: provably dead (softmax per-head, head 4 discarded)
  const float* Wa     = (const float*)d_in[24];
  const float* ba     = (const float*)d_in[25];
  const float* Wb     = (const float*)d_in[26];
  const float* bb     = (const float*)d_in[27];
  const float* Wg     = (const float*)d_in[28];
  const float* bg     = (const float*)d_in[29];
  float* out = (float*)d_out;
  float* ws  = (float*)d_ws;

  // ws layout (floats). Total ≈ 131 MB.
  float* seq    = ws;                       // 1,048,576
  float* x2seq  = ws +  1048576;            // 1,048,576
  float* qt     = ws +  2097152;            // 1,048,576 (mamba: W_xp 98,304)
  float* kt     = ws +  3145728;            // 1,048,576
  float* vt     = ws +  4194304;            // 1,048,576
  float* Abuf   = ws +  5242880;            // 2,097,152 (mamba: dtT)
  float* Bbuf   = ws +  7340032;            // 2,097,152 (mamba: dtuT)
  float* arena  = ws +  9437184;            // 16,777,216 (energy OR mamba chain)
  float* out2   = ws + 26214400;            // 1,048,576
  float* out1   = ws + 27262976;            // 1,048,576
  float* aproj  = ws + 28311552;            // 2,097,152 (vT parks here during attention)
  float* bproj  = ws + 30408704;            // 2,097,152
  float* gates  = ws + 32505856;            // 8,192
  float* W2     = ws + 32514048;            // 196,608
  // arena sub-layout (mamba phase):
  float* A2   = arena;                      // 3,145,728
  float* ctx  = arena +  3145728;           // 1,048,576
  float* xz   = arena +  4194304;           // 4,194,304
  float* xs   = arena +  8388608;           // 2,097,152
  float* xdbl = arena + 10485760;           // 786,432 (padded, stride 192)
  float* yT   = arena + 11272192;           // 2,097,152
  float* yb   = arena + 13369344;           // 2,097,152
  float* ym   = arena + 15466496;           // 1,048,576
  float* energy = arena;                    // 16,777,216 (attention phase)
  float* vT   = aproj;                      // 1,048,576 (attention phase only)
  float* dtT  = Abuf;                       // 2,097,152 (mamba phase only)
  float* dtuT = Bbuf;                       // 2,097,152 (mamba phase only)
  float* W_xp = qt;                         // 98,304    (mamba phase only)

  // 1. transpose x -> seq(+pos), x2seq
  k_transpose<<<dim3(32,16,4), dim3(32,8), 0, stream>>>(x, rh_c, rw_c, seq, x2seq);

  // ---- attention branch first (uses arena as energy) ----
  mgemm(stream, x2seq, Wq, qt, bq, 4096,256,256, 256,256,256, 0);
  mgemm(stream, x2seq, Wk, kt, bk, 4096,256,256, 256,256,256, 0);
  mgemm(stream, x2seq, Wv, vt, bv, 4096,256,256, 256,256,256, 0);
  k_pack_ab<<<8192, 256, 0, stream>>>(qt, kt, rhm, rwm, Abuf, Bbuf);
  k_vtrans<<<dim3(32,8,4), dim3(32,8), 0, stream>>>(vt, vT);
  // energy[z] = Abuf[z] @ Bbuf[z]^T  (M=N=1024, K=128), z = b*4+h  [128² tile]
  {
    dim3 g(8, 8, 16), blk(256);
    k_m128<<<g, blk, 0, stream>>>(Abuf, Bbuf, energy, nullptr,
        1024,1024,128, 128,128,1024,
        4L*131072, 131072, 4L*131072, 131072, 4L*1048576, 1048576, 0);
  }
  k_softmax<<<16384, 256, 0, stream>>>(energy);
  // PV via 64² kernel: out2[b,i,h*64+d] = sum_j attn[z][i,j] * vT[b, h*64+d, j]
  {
    dim3 g(1, 16, 16), blk(256);
    k_mgemmb<<<g, blk, 0, stream>>>(energy, vT, out2, nullptr,
        1024,64,1024, 1024,1024,256,
        4L*1048576, 1048576, 262144, 65536, 262144, 64, 0);
  }

  // ---- mamba branch (arena reused; Abuf/Bbuf/vT/qt free after PV) ----
  k_packw<<<768, 256, 0, stream>>>(gate_w, W2);
  k_padwx<<<384, 256, 0, stream>>>(W_x, W_xp);
  k_im2col<<<12288, 256, 0, stream>>>(seq, A2);
  mgemm(stream, A2, W2, ctx, gate_b, 4096,256,768, 768,768,256, 1);
  // xz = seq @ W_in^T   [128² tile]
  {
    dim3 g(8, 32, 1), blk(256);
    k_m128<<<g, blk, 0, stream>>>(seq, W_in, xz, nullptr,
        4096,1024,256, 256,256,1024, 0,0,0,0,0,0, 0);
  }
  k_dwconv<<<8192, 256, 0, stream>>>(xz, conv_w, conv_b, xs);
  // x_dbl = xs @ W_xp^T   (padded N=192 -> MFMA; xdbl stride 192)
  mgemm(stream, xs, W_xp, xdbl, nullptr, 4096,192,512, 512,512,XDW, 0);
  k_pret<<<dim3(32,16,4), dim3(32,8), 0, stream>>>(xdbl, xs, W_dt, b_dt, dtT, dtuT);
  // selective scan v6 (hand-pipelined serial phase)
  k_scan6<<<512, 256, 0, stream>>>(dtT, dtuT, xdbl, A_log, yT);
  k_ytrans<<<dim3(32,16,4), dim3(32,8), 0, stream>>>(yT, xs, xz, D_p, yb);
  mgemm(stream, yb, W_out, ym, nullptr, 4096,256,512, 512,512,256, 0);
  k_mulshuf<<<dim3(8,8,16), dim3(32,8), 0, stream>>>(ym, ctx, out1);

  // ---- fusion head ----
  mgemm(stream, out1, Wa, aproj, ba, 4096,512,256, 256,256,512, 0);
  mgemm(stream, out2, Wb, bproj, bb, 4096,512,256, 256,256,512, 0);
  k_gates<<<4096, 256, 0, stream>>>(aproj, bproj, Wg, bg, gates);
  k_final<<<2048, 256, 0, stream>>>(aproj, bproj, gates, out);
}